// Round 2
// baseline (480.831 us; speedup 1.0000x reference)
//
#include <hip/hip_runtime.h>
#include <stdint.h>

#define BATCH 4
#define HH 128
#define WW 128
#define CIN 256
#define CO 512
#define HP 130
#define NPIX (BATCH*HH*WW)          // 65536
#define LOGITS_N (NPIX*6)           // 393216
#define DELTA_BASE (2*LOGITS_N)     // 786432

typedef short bf16x8 __attribute__((ext_vector_type(8)));
typedef unsigned short u16x8 __attribute__((ext_vector_type(8)));
typedef float f32x4 __attribute__((ext_vector_type(4)));

__device__ __forceinline__ unsigned short f2bf(float f) {
    union { float f; unsigned int u; } v; v.f = f;
    return (unsigned short)((v.u + 0x7FFFu + ((v.u >> 16) & 1u)) >> 16);
}

// ---- pass 1a: fp32 input -> bf16 with 1-pixel zero halo: [B][130][130][256]
__global__ __launch_bounds__(256) void k_pad_convert(const float* __restrict__ in,
                                                     unsigned short* __restrict__ out) {
    int pix = blockIdx.x;                 // (b, yy, xx), xx fastest
    int xx = pix % HP; int t = pix / HP; int yy = t % HP; int b = t / HP;
    int c = threadIdx.x;
    unsigned short val = 0;
    if (yy >= 1 && yy <= HH && xx >= 1 && xx <= WW) {
        val = f2bf(in[(((size_t)(b*HH) + (yy-1))*WW + (xx-1))*CIN + c]);
    }
    out[(size_t)pix*CIN + c] = val;
}

// ---- pass 1b: w_shared [9][256][512] fp32 -> wT [9][512][256] bf16
__global__ __launch_bounds__(256) void k_wt_convert(const float* __restrict__ w,
                                                    unsigned short* __restrict__ wt) {
    int n = blockIdx.x % CO; int tap = blockIdx.x / CO;
    int c = threadIdx.x;
    wt[((size_t)tap*CO + n)*CIN + c] = f2bf(w[((size_t)tap*CIN + c)*CO + n]);
}

// ---- main: implicit-GEMM conv (M=65536,N=512,K=2304) + fused 1x1 heads (partials via atomics)
template<int USE_WS>
__global__ __launch_bounds__(256) void k_main(
    const unsigned short* __restrict__ in_p,   // bf16 padded input (USE_WS)
    const unsigned short* __restrict__ wt,     // bf16 wT (USE_WS)
    const float* __restrict__ in_f,            // fp32 input (!USE_WS)
    const float* __restrict__ w_f,             // fp32 w_shared (!USE_WS)
    const float* __restrict__ b_sh,
    const float* __restrict__ w_cls,
    const float* __restrict__ w_dlt,
    float* __restrict__ out)
{
    __shared__ float smemf[11008];             // 44032 B: A(16K) B(16K) | shf(33792) + sW(10240)
    char* smem  = (char*)smemf;
    char* smemB = smem + 16384;

    const int tid = threadIdx.x;
    const int lane = tid & 63, wave = tid >> 6;
    const int l15 = lane & 15, l4 = lane >> 4;
    const int wr = wave >> 1, wc = wave & 1;

    // XCD-contiguous swizzle (2048 % 8 == 0 -> bijective)
    int bid = ((blockIdx.x & 7) << 8) + (blockIdx.x >> 3);
    const int ntile = bid & 3, mtile = bid >> 2;
    const int n0 = ntile << 7;
    const int b = mtile >> 7, y = mtile & 127;

    // swizzled LDS byte offsets for MFMA fragment reads
    int aoff[4][2], boff[4][2];
    #pragma unroll
    for (int mi = 0; mi < 4; mi++) {
        int rowA = wr*64 + mi*16 + l15;
        int rowB = wc*64 + mi*16 + l15;
        #pragma unroll
        for (int kk = 0; kk < 2; kk++) {
            int kb = (kk*32 + l4*8) * 2;
            aoff[mi][kk] = rowA*128 + (kb ^ ((rowA & 7) << 4));
            boff[mi][kk] = rowB*128 + (kb ^ ((rowB & 7) << 4));
        }
    }

    f32x4 acc[4][4];
    const f32x4 zz = {0.f, 0.f, 0.f, 0.f};
    #pragma unroll
    for (int mi = 0; mi < 4; mi++)
        #pragma unroll
        for (int ni = 0; ni < 4; ni++) acc[mi][ni] = zz;

    for (int tap = 0; tap < 9; tap++) {
        const int dy = tap / 3, dx = tap % 3;
        for (int kq = 0; kq < 4; kq++) {
            const int c0 = kq * 64;
            if (USE_WS) {
                const unsigned short* srcA = in_p + (((size_t)(b*HP + y + dy))*HP + dx)*CIN + c0;
                const unsigned short* srcB = wt   + ((size_t)tap*CO + n0)*CIN + c0;
                #pragma unroll
                for (int i = 0; i < 4; i++) {
                    int ci = i*256 + tid;
                    int row = ci >> 3, pc = ci & 7;
                    int kc = pc ^ (row & 7);                     // inverse swizzle on source
                    u16x8 a  = *(const u16x8*)(srcA + (size_t)row*CIN + kc*8);
                    u16x8 bb = *(const u16x8*)(srcB + (size_t)row*CIN + kc*8);
                    *(u16x8*)(smem  + ci*16) = a;                // linear LDS write: conflict-free
                    *(u16x8*)(smemB + ci*16) = bb;
                }
            } else {
                const int yy = y + dy - 1;
                const bool yok = (yy >= 0) && (yy < HH);
                #pragma unroll
                for (int i = 0; i < 4; i++) {
                    int ci = i*256 + tid;
                    int row = ci >> 3, pc = ci & 7;
                    int kc = pc ^ (row & 7);
                    int xx = row + dx - 1;
                    u16x8 a;
                    if (yok && xx >= 0 && xx < WW) {
                        const float* s = in_f + (((size_t)(b*HH) + yy)*WW + xx)*CIN + c0 + kc*8;
                        #pragma unroll
                        for (int j = 0; j < 8; j++) a[j] = (short)f2bf(s[j]);
                    } else {
                        #pragma unroll
                        for (int j = 0; j < 8; j++) a[j] = 0;
                    }
                    *(u16x8*)(smem + ci*16) = a;
                    const float* wsrc = w_f + ((size_t)(tap*CIN + c0 + kc*8))*CO + n0 + row;
                    u16x8 bb;
                    #pragma unroll
                    for (int j = 0; j < 8; j++) bb[j] = (short)f2bf(wsrc[(size_t)j*CO]);
                    *(u16x8*)(smemB + ci*16) = bb;
                }
            }
            __syncthreads();
            #pragma unroll
            for (int kk = 0; kk < 2; kk++) {
                bf16x8 av[4], bv[4];
                #pragma unroll
                for (int mi = 0; mi < 4; mi++) av[mi] = *(const bf16x8*)(smem  + aoff[mi][kk]);
                #pragma unroll
                for (int ni = 0; ni < 4; ni++) bv[ni] = *(const bf16x8*)(smemB + boff[ni][kk]);
                #pragma unroll
                for (int mi = 0; mi < 4; mi++)
                    #pragma unroll
                    for (int ni = 0; ni < 4; ni++)
                        acc[mi][ni] = __builtin_amdgcn_mfma_f32_16x16x32_bf16(
                            av[mi], bv[ni], acc[mi][ni], 0, 0, 0);
            }
            __syncthreads();
        }
    }

    // ---- epilogue: bias+ReLU, then 1x1-head partial reduction over this wg's 128 channels
    float* shf = smemf;            // [64 cols][132]
    float* sW  = smemf + 8448;     // [128][20]
    for (int j = tid; j < 128*18; j += 256) {
        int c = j / 18, o = j - c*18;
        sW[c*20 + o] = (o < 6) ? w_cls[(size_t)(n0 + c)*6 + o]
                               : w_dlt[(size_t)(n0 + c)*12 + (o - 6)];
    }
    float bsh[4];
    #pragma unroll
    for (int ni = 0; ni < 4; ni++) bsh[ni] = b_sh[n0 + wc*64 + ni*16 + l15];

    float a18[18];
    #pragma unroll
    for (int o = 0; o < 18; o++) a18[o] = 0.f;
    const int rr = tid & 127, chalf = tid >> 7;

    #pragma unroll
    for (int pass = 0; pass < 2; pass++) {
        if (wc == pass) {
            #pragma unroll
            for (int mi = 0; mi < 4; mi++)
                #pragma unroll
                for (int ni = 0; ni < 4; ni++) {
                    int colL = ni*16 + l15;
                    int row0 = wr*64 + mi*16 + l4*4;
                    f32x4 v = acc[mi][ni];
                    f32x4 s;
                    #pragma unroll
                    for (int r = 0; r < 4; r++) s[r] = fmaxf(v[r] + bsh[ni], 0.f);
                    *(f32x4*)(shf + colL*132 + row0) = s;
                }
        }
        __syncthreads();
        #pragma unroll 4
        for (int i = 0; i < 32; i++) {
            int c = chalf*32 + i;
            float v = shf[c*132 + rr];
            const float* wrow = sW + (pass*64 + c)*20;   // FIX: channel = n0 + pass*64 + c
            #pragma unroll
            for (int o = 0; o < 18; o++) a18[o] += v * wrow[o];
        }
        __syncthreads();
    }

    const int pixel = mtile*128 + rr;
    float* lo = out + (size_t)pixel*6;
    float* dl = out + DELTA_BASE + (size_t)pixel*12;
    #pragma unroll
    for (int o = 0; o < 6; o++)  atomicAdd(lo + o, a18[o]);
    #pragma unroll
    for (int o = 0; o < 12; o++) atomicAdd(dl + o, a18[6 + o]);
}

// ---- finalize: add head biases, softmax -> probs
__global__ __launch_bounds__(256) void k_finalize(float* __restrict__ out,
                                                  const float* __restrict__ b_cls,
                                                  const float* __restrict__ b_dlt) {
    int pix = blockIdx.x*256 + threadIdx.x;
    if (pix >= NPIX) return;
    float* lo = out + (size_t)pix*6;
    float* pr = out + (size_t)LOGITS_N + (size_t)pix*6;
    float* dl = out + (size_t)DELTA_BASE + (size_t)pix*12;
    #pragma unroll
    for (int a = 0; a < 3; a++) {
        float l0 = lo[a*2]   + b_cls[a*2];
        float l1 = lo[a*2+1] + b_cls[a*2+1];
        lo[a*2] = l0; lo[a*2+1] = l1;
        float m = fmaxf(l0, l1);
        float e0 = __expf(l0 - m), e1 = __expf(l1 - m);
        float inv = 1.f / (e0 + e1);
        pr[a*2] = e0*inv; pr[a*2+1] = e1*inv;
    }
    #pragma unroll
    for (int o = 0; o < 12; o++) dl[o] += b_dlt[o];
}

extern "C" void kernel_launch(void* const* d_in, const int* in_sizes, int n_in,
                              void* d_out, int out_size, void* d_ws, size_t ws_size,
                              hipStream_t stream) {
    const float* in    = (const float*)d_in[0];
    const float* w_sh  = (const float*)d_in[1];
    const float* b_sh  = (const float*)d_in[2];
    const float* w_cls = (const float*)d_in[3];
    const float* b_cls = (const float*)d_in[4];
    const float* w_dlt = (const float*)d_in[5];
    const float* b_dlt = (const float*)d_in[6];
    float* out = (float*)d_out;

    hipMemsetAsync(d_out, 0, (size_t)out_size * sizeof(float), stream);

    const size_t in_p_elems = (size_t)BATCH*HP*HP*CIN;   // 17,305,600
    const size_t wt_elems   = (size_t)9*CO*CIN;          // 1,179,648
    const size_t need = (in_p_elems + wt_elems) * 2;     // ~35.3 MB

    if (ws_size >= need) {
        unsigned short* in_p = (unsigned short*)d_ws;
        unsigned short* wt   = in_p + in_p_elems;
        k_pad_convert<<<BATCH*HP*HP, 256, 0, stream>>>(in, in_p);
        k_wt_convert<<<9*CO, 256, 0, stream>>>(w_sh, wt);
        k_main<1><<<2048, 256, 0, stream>>>(in_p, wt, nullptr, nullptr,
                                            b_sh, w_cls, w_dlt, out);
    } else {
        k_main<0><<<2048, 256, 0, stream>>>(nullptr, nullptr, in, w_sh,
                                            b_sh, w_cls, w_dlt, out);
    }
    k_finalize<<<(NPIX + 255)/256, 256, 0, stream>>>(out, b_cls, b_dlt);
}

// Round 3
// 325.217 us; speedup vs baseline: 1.4785x; 1.4785x over previous
//
#include <hip/hip_runtime.h>
#include <stdint.h>

#define BATCH 4
#define HH 128
#define WW 128
#define CIN 256
#define CO 512
#define HP 130
#define NPIX (BATCH*HH*WW)          // 65536
#define LOGITS_N (NPIX*6)           // 393216
#define DELTA_BASE (2*LOGITS_N)     // 786432

typedef short bf16x8 __attribute__((ext_vector_type(8)));
typedef unsigned short u16x8 __attribute__((ext_vector_type(8)));
typedef float f32x4 __attribute__((ext_vector_type(4)));
typedef unsigned int u32;

__device__ __forceinline__ unsigned short f2bf(float f) {
    union { float f; unsigned int u; } v; v.f = f;
    return (unsigned short)((v.u + 0x7FFFu + ((v.u >> 16) & 1u)) >> 16);
}

// async global->LDS, 16 bytes per lane; dest must be lane-linear (it is: base + lane*16)
__device__ __forceinline__ void gload16(const unsigned short* g, unsigned short* l) {
    __builtin_amdgcn_global_load_lds(
        (const __attribute__((address_space(1))) u32*)g,
        (__attribute__((address_space(3))) u32*)l, 16, 0, 0);
}

// ---- pass 1a: fp32 input -> bf16 with 1-pixel zero halo: [B][130][130][256]
__global__ __launch_bounds__(256) void k_pad_convert(const float* __restrict__ in,
                                                     unsigned short* __restrict__ out) {
    size_t q = (size_t)blockIdx.x*256 + threadIdx.x;     // quad index (4 channels)
    if (q >= (size_t)BATCH*HP*HP*64) return;
    int c4 = ((int)q & 63) * 4;
    int pix = (int)(q >> 6);
    int xx = pix % HP; int t = pix / HP; int yy = t % HP; int b = t / HP;
    ushort4 r = {0, 0, 0, 0};
    if (yy >= 1 && yy <= HH && xx >= 1 && xx <= WW) {
        const float4 v = *(const float4*)(in + (((size_t)(b*HH) + (yy-1))*WW + (xx-1))*CIN + c4);
        r.x = f2bf(v.x); r.y = f2bf(v.y); r.z = f2bf(v.z); r.w = f2bf(v.w);
    }
    *(ushort4*)(out + (size_t)pix*CIN + c4) = r;
}

// ---- pass 1b: w_shared [9][256][512] fp32 -> wT [9][512][256] bf16
__global__ __launch_bounds__(256) void k_wt_convert(const float* __restrict__ w,
                                                    unsigned short* __restrict__ wt) {
    int n = blockIdx.x % CO; int tap = blockIdx.x / CO;
    int c = threadIdx.x;
    wt[((size_t)tap*CO + n)*CIN + c] = f2bf(w[((size_t)tap*CIN + c)*CO + n]);
}

// ---- main: implicit-GEMM conv (M=65536,N=512,K=2304) + fused 1x1 heads
template<int USE_WS>
__global__ __launch_bounds__(256) void k_main(
    const unsigned short* __restrict__ in_p,   // bf16 padded input (USE_WS)
    const unsigned short* __restrict__ wt,     // bf16 wT (USE_WS)
    const float* __restrict__ in_f,            // fp32 input (!USE_WS)
    const float* __restrict__ w_f,             // fp32 w_shared (!USE_WS)
    const float* __restrict__ b_sh,
    const float* __restrict__ w_cls,
    const float* __restrict__ w_dlt,
    float* __restrict__ out,                   // d_out (fallback atomics) 
    float* __restrict__ part)                  // ws partials [4][NPIX][18] (USE_WS)
{
    __shared__ float smemf[11008];             // 44032 B: A(16K) B(16K) | shf(33792)+sW(10240)
    char* smem  = (char*)smemf;
    char* smemB = smem + 16384;

    const int tid = threadIdx.x;
    const int lane = tid & 63, wave = tid >> 6;
    const int l15 = lane & 15, l4 = lane >> 4;
    const int wr = wave >> 1, wc = wave & 1;

    // XCD-contiguous swizzle (2048 % 8 == 0 -> bijective)
    int bid = ((blockIdx.x & 7) << 8) + (blockIdx.x >> 3);
    const int ntile = bid & 3, mtile = bid >> 2;
    const int n0 = ntile << 7;
    const int b = mtile >> 7, y = mtile & 127;

    // swizzled LDS byte offsets for MFMA fragment reads
    int aoff[4][2], boff[4][2];
    #pragma unroll
    for (int mi = 0; mi < 4; mi++) {
        int rowA = wr*64 + mi*16 + l15;
        int rowB = wc*64 + mi*16 + l15;
        #pragma unroll
        for (int kk = 0; kk < 2; kk++) {
            int kb = (kk*32 + l4*8) * 2;
            aoff[mi][kk] = rowA*128 + (kb ^ ((rowA & 7) << 4));
            boff[mi][kk] = rowB*128 + (kb ^ ((rowB & 7) << 4));
        }
    }

    f32x4 acc[4][4];
    const f32x4 zz = {0.f, 0.f, 0.f, 0.f};
    #pragma unroll
    for (int mi = 0; mi < 4; mi++)
        #pragma unroll
        for (int ni = 0; ni < 4; ni++) acc[mi][ni] = zz;

    // hoisted per-thread staging pointers (loop-invariant: depend only on tid,i)
    const unsigned short* pA[4]; const unsigned short* pB[4];
    unsigned short* pL[4]; unsigned short* pLB[4];
    #pragma unroll
    for (int i = 0; i < 4; i++) {
        int ci = i*256 + tid;
        int row = ci >> 3, pc = ci & 7;
        int kc = pc ^ (row & 7);                 // inverse swizzle applied on SOURCE
        if (USE_WS) {
            pA[i] = in_p + (size_t)row*CIN + kc*8;
            pB[i] = wt   + (size_t)row*CIN + kc*8;
        }
        pL[i]  = (unsigned short*)(smem  + ci*16);   // linear LDS dest
        pLB[i] = (unsigned short*)(smemB + ci*16);
    }

    for (int tap = 0; tap < 9; tap++) {
        const int dy = tap / 3, dx = tap % 3;
        for (int kq = 0; kq < 4; kq++) {
            const int c0 = kq * 64;
            if (USE_WS) {
                const size_t offA = (((size_t)(b*HP + y + dy))*HP + dx)*CIN + c0;  // uniform
                const size_t offB = ((size_t)tap*CO + n0)*CIN + c0;                // uniform
                #pragma unroll
                for (int i = 0; i < 4; i++) {
                    gload16(pA[i] + offA, pL[i]);
                    gload16(pB[i] + offB, pLB[i]);
                }
            } else {
                const int yy = y + dy - 1;
                const bool yok = (yy >= 0) && (yy < HH);
                #pragma unroll
                for (int i = 0; i < 4; i++) {
                    int ci = i*256 + tid;
                    int row = ci >> 3, pc = ci & 7;
                    int kc = pc ^ (row & 7);
                    int xx = row + dx - 1;
                    u16x8 a;
                    if (yok && xx >= 0 && xx < WW) {
                        const float* s = in_f + (((size_t)(b*HH) + yy)*WW + xx)*CIN + c0 + kc*8;
                        #pragma unroll
                        for (int j = 0; j < 8; j++) a[j] = (short)f2bf(s[j]);
                    } else {
                        #pragma unroll
                        for (int j = 0; j < 8; j++) a[j] = 0;
                    }
                    *(u16x8*)(smem + ci*16) = a;
                    const float* wsrc = w_f + ((size_t)(tap*CIN + c0 + kc*8))*CO + n0 + row;
                    u16x8 bb;
                    #pragma unroll
                    for (int j = 0; j < 8; j++) bb[j] = (short)f2bf(wsrc[(size_t)j*CO]);
                    *(u16x8*)(smemB + ci*16) = bb;
                }
            }
            __syncthreads();
            #pragma unroll
            for (int kk = 0; kk < 2; kk++) {
                bf16x8 av[4], bv[4];
                #pragma unroll
                for (int mi = 0; mi < 4; mi++) av[mi] = *(const bf16x8*)(smem  + aoff[mi][kk]);
                #pragma unroll
                for (int ni = 0; ni < 4; ni++) bv[ni] = *(const bf16x8*)(smemB + boff[ni][kk]);
                #pragma unroll
                for (int mi = 0; mi < 4; mi++)
                    #pragma unroll
                    for (int ni = 0; ni < 4; ni++)
                        acc[mi][ni] = __builtin_amdgcn_mfma_f32_16x16x32_bf16(
                            av[mi], bv[ni], acc[mi][ni], 0, 0, 0);
            }
            __syncthreads();
        }
    }

    // ---- epilogue: bias+ReLU, 1x1-head partial reduction over this wg's 128 channels
    float* shf = smemf;            // [64 cols][132]
    float* sW  = smemf + 8448;     // [128][20]
    for (int j = tid; j < 128*18; j += 256) {
        int c = j / 18, o = j - c*18;
        sW[c*20 + o] = (o < 6) ? w_cls[(size_t)(n0 + c)*6 + o]
                               : w_dlt[(size_t)(n0 + c)*12 + (o - 6)];
    }
    float bsh[4];
    #pragma unroll
    for (int ni = 0; ni < 4; ni++) bsh[ni] = b_sh[n0 + wc*64 + ni*16 + l15];

    float a18[18];
    #pragma unroll
    for (int o = 0; o < 18; o++) a18[o] = 0.f;
    const int rr = tid & 127, chalf = tid >> 7;

    #pragma unroll
    for (int pass = 0; pass < 2; pass++) {
        if (wc == pass) {
            #pragma unroll
            for (int mi = 0; mi < 4; mi++)
                #pragma unroll
                for (int ni = 0; ni < 4; ni++) {
                    int colL = ni*16 + l15;
                    int row0 = wr*64 + mi*16 + l4*4;
                    f32x4 v = acc[mi][ni];
                    f32x4 s;
                    #pragma unroll
                    for (int r = 0; r < 4; r++) s[r] = fmaxf(v[r] + bsh[ni], 0.f);
                    *(f32x4*)(shf + colL*132 + row0) = s;
                }
        }
        __syncthreads();
        #pragma unroll 4
        for (int i = 0; i < 32; i++) {
            int c = chalf*32 + i;
            float v = shf[c*132 + rr];
            const float* wrow = sW + (pass*64 + c)*20;   // channel = n0 + pass*64 + c
            #pragma unroll
            for (int o = 0; o < 18; o++) a18[o] += v * wrow[o];
        }
        __syncthreads();
    }

    const int pixel = mtile*128 + rr;
    if (USE_WS) {
        // combine chalf halves via LDS, then one clean partial write (no atomics)
        if (chalf == 1) {
            #pragma unroll
            for (int o = 0; o < 18; o++) shf[rr*18 + o] = a18[o];
        }
        __syncthreads();
        if (chalf == 0) {
            float* dst = part + ((size_t)ntile*NPIX + pixel)*18;
            #pragma unroll
            for (int o = 0; o < 18; o++) dst[o] = a18[o] + shf[rr*18 + o];
        }
    } else {
        float* lo = out + (size_t)pixel*6;
        float* dl = out + DELTA_BASE + (size_t)pixel*12;
        #pragma unroll
        for (int o = 0; o < 6; o++)  atomicAdd(lo + o, a18[o]);
        #pragma unroll
        for (int o = 0; o < 12; o++) atomicAdd(dl + o, a18[6 + o]);
    }
}

// ---- finalize (ws path): sum 4 partials, biases, softmax -> all outputs
__global__ __launch_bounds__(256) void k_finalize_ws(const float* __restrict__ part,
                                                     float* __restrict__ out,
                                                     const float* __restrict__ b_cls,
                                                     const float* __restrict__ b_dlt) {
    int pix = blockIdx.x*256 + threadIdx.x;
    if (pix >= NPIX) return;
    float s[18];
    #pragma unroll
    for (int o = 0; o < 18; o++) s[o] = 0.f;
    #pragma unroll
    for (int nt = 0; nt < 4; nt++) {
        const float* p = part + ((size_t)nt*NPIX + pix)*18;
        #pragma unroll
        for (int o = 0; o < 18; o++) s[o] += p[o];
    }
    float* lo = out + (size_t)pix*6;
    float* pr = out + (size_t)LOGITS_N + (size_t)pix*6;
    float* dl = out + (size_t)DELTA_BASE + (size_t)pix*12;
    #pragma unroll
    for (int a = 0; a < 3; a++) {
        float l0 = s[a*2]   + b_cls[a*2];
        float l1 = s[a*2+1] + b_cls[a*2+1];
        lo[a*2] = l0; lo[a*2+1] = l1;
        float m = fmaxf(l0, l1);
        float e0 = __expf(l0 - m), e1 = __expf(l1 - m);
        float inv = 1.f / (e0 + e1);
        pr[a*2] = e0*inv; pr[a*2+1] = e1*inv;
    }
    #pragma unroll
    for (int o = 0; o < 12; o++) dl[o] = s[6 + o] + b_dlt[o];
}

// ---- finalize (fallback path): logits already in out via atomics
__global__ __launch_bounds__(256) void k_finalize(float* __restrict__ out,
                                                  const float* __restrict__ b_cls,
                                                  const float* __restrict__ b_dlt) {
    int pix = blockIdx.x*256 + threadIdx.x;
    if (pix >= NPIX) return;
    float* lo = out + (size_t)pix*6;
    float* pr = out + (size_t)LOGITS_N + (size_t)pix*6;
    float* dl = out + (size_t)DELTA_BASE + (size_t)pix*12;
    #pragma unroll
    for (int a = 0; a < 3; a++) {
        float l0 = lo[a*2]   + b_cls[a*2];
        float l1 = lo[a*2+1] + b_cls[a*2+1];
        lo[a*2] = l0; lo[a*2+1] = l1;
        float m = fmaxf(l0, l1);
        float e0 = __expf(l0 - m), e1 = __expf(l1 - m);
        float inv = 1.f / (e0 + e1);
        pr[a*2] = e0*inv; pr[a*2+1] = e1*inv;
    }
    #pragma unroll
    for (int o = 0; o < 12; o++) dl[o] += b_dlt[o];
}

extern "C" void kernel_launch(void* const* d_in, const int* in_sizes, int n_in,
                              void* d_out, int out_size, void* d_ws, size_t ws_size,
                              hipStream_t stream) {
    const float* in    = (const float*)d_in[0];
    const float* w_sh  = (const float*)d_in[1];
    const float* b_sh  = (const float*)d_in[2];
    const float* w_cls = (const float*)d_in[3];
    const float* b_cls = (const float*)d_in[4];
    const float* w_dlt = (const float*)d_in[5];
    const float* b_dlt = (const float*)d_in[6];
    float* out = (float*)d_out;

    const size_t in_p_elems = (size_t)BATCH*HP*HP*CIN;   // 17,305,600
    const size_t wt_elems   = (size_t)9*CO*CIN;          // 1,179,648
    const size_t part_elems = (size_t)4*NPIX*18;         // 4,718,592
    const size_t need = (in_p_elems + wt_elems)*2 + part_elems*4;  // ~54.7 MB

    if (ws_size >= need) {
        unsigned short* in_p = (unsigned short*)d_ws;
        unsigned short* wt   = in_p + in_p_elems;
        float* part = (float*)(wt + wt_elems);
        int padq = (int)(((size_t)BATCH*HP*HP*64 + 255)/256);
        k_pad_convert<<<padq, 256, 0, stream>>>(in, in_p);
        k_wt_convert<<<9*CO, 256, 0, stream>>>(w_sh, wt);
        k_main<1><<<2048, 256, 0, stream>>>(in_p, wt, nullptr, nullptr,
                                            b_sh, w_cls, w_dlt, out, part);
        k_finalize_ws<<<(NPIX + 255)/256, 256, 0, stream>>>(part, out, b_cls, b_dlt);
    } else {
        hipMemsetAsync(d_out, 0, (size_t)out_size * sizeof(float), stream);
        k_main<0><<<2048, 256, 0, stream>>>(nullptr, nullptr, in, w_sh,
                                            b_sh, w_cls, w_dlt, out, nullptr);
        k_finalize<<<(NPIX + 255)/256, 256, 0, stream>>>(out, b_cls, b_dlt);
    }
}

// Round 4
// 222.464 us; speedup vs baseline: 2.1614x; 1.4619x over previous
//
#include <hip/hip_runtime.h>
#include <stdint.h>

#define BATCH 4
#define HH 128
#define WW 128
#define CIN 256
#define CO 512
#define HP 130
#define NPIX (BATCH*HH*WW)          // 65536
#define LOGITS_N (NPIX*6)           // 393216
#define DELTA_BASE (2*LOGITS_N)     // 786432

typedef short bf16x8 __attribute__((ext_vector_type(8)));
typedef unsigned short u16x8 __attribute__((ext_vector_type(8)));
typedef float f32x4 __attribute__((ext_vector_type(4)));
typedef unsigned int u32;

__device__ __forceinline__ unsigned short f2bf(float f) {
    union { float f; unsigned int u; } v; v.f = f;
    return (unsigned short)((v.u + 0x7FFFu + ((v.u >> 16) & 1u)) >> 16);
}

// async global->LDS, 16 bytes per lane; dest must be lane-linear (base + lane*16)
__device__ __forceinline__ void gload16(const unsigned short* g, unsigned short* l) {
    __builtin_amdgcn_global_load_lds(
        (const __attribute__((address_space(1))) u32*)g,
        (__attribute__((address_space(3))) u32*)l, 16, 0, 0);
}

// ---- pass 1a: fp32 input -> bf16 with 1-pixel zero halo: [B][130][130][256]
__global__ __launch_bounds__(256) void k_pad_convert(const float* __restrict__ in,
                                                     unsigned short* __restrict__ out) {
    size_t q = (size_t)blockIdx.x*256 + threadIdx.x;     // quad index (4 channels)
    if (q >= (size_t)BATCH*HP*HP*64) return;
    int c4 = ((int)q & 63) * 4;
    int pix = (int)(q >> 6);
    int xx = pix % HP; int t = pix / HP; int yy = t % HP; int b = t / HP;
    ushort4 r = {0, 0, 0, 0};
    if (yy >= 1 && yy <= HH && xx >= 1 && xx <= WW) {
        const float4 v = *(const float4*)(in + (((size_t)(b*HH) + (yy-1))*WW + (xx-1))*CIN + c4);
        r.x = f2bf(v.x); r.y = f2bf(v.y); r.z = f2bf(v.z); r.w = f2bf(v.w);
    }
    *(ushort4*)(out + (size_t)pix*CIN + c4) = r;
}

// ---- pass 1b: w_shared [9][256][512] fp32 -> wT [9][512][256] bf16
__global__ __launch_bounds__(256) void k_wt_convert(const float* __restrict__ w,
                                                    unsigned short* __restrict__ wt) {
    int n = blockIdx.x % CO; int tap = blockIdx.x / CO;
    int c = threadIdx.x;
    wt[((size_t)tap*CO + n)*CIN + c] = f2bf(w[((size_t)tap*CIN + c)*CO + n]);
}

// ---- main: implicit-GEMM conv (M=65536,N=512,K=2304) + fused 1x1 heads
// 2-phase double-buffered pipeline: STAGE(t+1) || compute(t), one barrier/step.
template<int USE_WS>
__global__ __launch_bounds__(256) void k_main(
    const unsigned short* __restrict__ in_p,   // bf16 padded input (USE_WS)
    const unsigned short* __restrict__ wt,     // bf16 wT (USE_WS)
    const float* __restrict__ in_f,            // fp32 input (!USE_WS)
    const float* __restrict__ w_f,             // fp32 w_shared (!USE_WS)
    const float* __restrict__ b_sh,
    const float* __restrict__ w_cls,
    const float* __restrict__ w_dlt,
    float* __restrict__ out,                   // d_out (fallback atomics)
    float* __restrict__ part)                  // ws partials [4][NPIX][18] (USE_WS)
{
    __shared__ float smemf[16384];             // 64 KB: [A0 16K][B0 16K][A1 16K][B1 16K]
    char* base = (char*)smemf;

    const int tid = threadIdx.x;
    const int lane = tid & 63, wave = tid >> 6;
    const int l15 = lane & 15, l4 = lane >> 4;
    const int wr = wave >> 1, wc = wave & 1;

    // XCD-contiguous swizzle (2048 % 8 == 0 -> bijective)
    int bid = ((blockIdx.x & 7) << 8) + (blockIdx.x >> 3);
    const int ntile = bid & 3, mtile = bid >> 2;
    const int n0 = ntile << 7;
    const int b = mtile >> 7, y = mtile & 127;

    // swizzled LDS byte offsets (within one A/B buffer) for MFMA fragment reads
    int aoff[4][2], boff[4][2];
    #pragma unroll
    for (int mi = 0; mi < 4; mi++) {
        int rowA = wr*64 + mi*16 + l15;
        int rowB = wc*64 + mi*16 + l15;
        #pragma unroll
        for (int kk = 0; kk < 2; kk++) {
            int kb = (kk*32 + l4*8) * 2;
            aoff[mi][kk] = rowA*128 + (kb ^ ((rowA & 7) << 4));
            boff[mi][kk] = rowB*128 + (kb ^ ((rowB & 7) << 4));
        }
    }

    f32x4 acc[4][4];
    const f32x4 zz = {0.f, 0.f, 0.f, 0.f};
    #pragma unroll
    for (int mi = 0; mi < 4; mi++)
        #pragma unroll
        for (int ni = 0; ni < 4; ni++) acc[mi][ni] = zz;

    // hoisted per-thread staging pointers (depend only on tid,i)
    const unsigned short* pA[4]; const unsigned short* pB[4];
    int ldsOff[4];
    #pragma unroll
    for (int i = 0; i < 4; i++) {
        int ci = i*256 + tid;
        int row = ci >> 3, pc = ci & 7;
        int kc = pc ^ (row & 7);                 // inverse swizzle applied on SOURCE
        if (USE_WS) {
            pA[i] = in_p + (size_t)row*CIN + kc*8;
            pB[i] = wt   + (size_t)row*CIN + kc*8;
        }
        ldsOff[i] = ci*16;                       // linear LDS dest (lane-contiguous)
    }

    if (USE_WS) {
        // ---- software-pipelined K-loop: 36 steps (9 taps x 4 kq), BK=64
        auto STAGE = [&](int s, int cur) {
            int tap = s >> 2, kq = s & 3;
            int dy = tap / 3, dx = tap - dy*3;
            size_t offA = (((size_t)(b*HP + y + dy))*HP + dx)*CIN + kq*64;  // wave-uniform
            size_t offB = ((size_t)tap*CO + n0)*CIN + kq*64;                // wave-uniform
            char* dA = base + cur*32768;
            char* dB = dA + 16384;
            #pragma unroll
            for (int i = 0; i < 4; i++) {
                gload16(pA[i] + offA, (unsigned short*)(dA + ldsOff[i]));
                gload16(pB[i] + offB, (unsigned short*)(dB + ldsOff[i]));
            }
        };

        STAGE(0, 0);
        __syncthreads();                 // compiler emits vmcnt(0) before s_barrier: buf0 ready

        for (int s = 0; s < 36; s++) {
            const int cur = s & 1;
            if (s < 35) STAGE(s + 1, cur ^ 1);   // prefetch rides under compute
            char* smem  = base + cur*32768;
            char* smemB = smem + 16384;
            #pragma unroll
            for (int kk = 0; kk < 2; kk++) {
                bf16x8 av[4], bv[4];
                #pragma unroll
                for (int mi = 0; mi < 4; mi++) av[mi] = *(const bf16x8*)(smem  + aoff[mi][kk]);
                #pragma unroll
                for (int ni = 0; ni < 4; ni++) bv[ni] = *(const bf16x8*)(smemB + boff[ni][kk]);
                #pragma unroll
                for (int mi = 0; mi < 4; mi++)
                    #pragma unroll
                    for (int ni = 0; ni < 4; ni++)
                        acc[mi][ni] = __builtin_amdgcn_mfma_f32_16x16x32_bf16(
                            av[mi], bv[ni], acc[mi][ni], 0, 0, 0);
            }
            // one barrier per step; compiler's vmcnt(0)+lgkmcnt(0) drain before s_barrier
            // orders: (a) next-tile gload_lds complete, (b) this tile's ds_reads done
            // before anyone overwrites this buffer at s+2.
            __syncthreads();
        }
    } else {
        // fallback: synchronous single-buffer staging (stage -> barrier -> compute -> barrier)
        for (int s = 0; s < 36; s++) {
            int tap = s >> 2, kq = s & 3;
            int dy = tap / 3, dx = tap - dy*3;
            const int c0 = kq * 64;
            char* smem  = base;
            char* smemB = base + 16384;
            const int yy = y + dy - 1;
            const bool yok = (yy >= 0) && (yy < HH);
            #pragma unroll
            for (int i = 0; i < 4; i++) {
                int ci = i*256 + tid;
                int row = ci >> 3, pc = ci & 7;
                int kc = pc ^ (row & 7);
                int xx = row + dx - 1;
                u16x8 a;
                if (yok && xx >= 0 && xx < WW) {
                    const float* sp = in_f + (((size_t)(b*HH) + yy)*WW + xx)*CIN + c0 + kc*8;
                    #pragma unroll
                    for (int j = 0; j < 8; j++) a[j] = (short)f2bf(sp[j]);
                } else {
                    #pragma unroll
                    for (int j = 0; j < 8; j++) a[j] = 0;
                }
                *(u16x8*)(smem + ci*16) = a;
                const float* wsrc = w_f + ((size_t)(tap*CIN + c0 + kc*8))*CO + n0 + row;
                u16x8 bb;
                #pragma unroll
                for (int j = 0; j < 8; j++) bb[j] = (short)f2bf(wsrc[(size_t)j*CO]);
                *(u16x8*)(smemB + ci*16) = bb;
            }
            __syncthreads();
            #pragma unroll
            for (int kk = 0; kk < 2; kk++) {
                bf16x8 av[4], bv[4];
                #pragma unroll
                for (int mi = 0; mi < 4; mi++) av[mi] = *(const bf16x8*)(smem  + aoff[mi][kk]);
                #pragma unroll
                for (int ni = 0; ni < 4; ni++) bv[ni] = *(const bf16x8*)(smemB + boff[ni][kk]);
                #pragma unroll
                for (int mi = 0; mi < 4; mi++)
                    #pragma unroll
                    for (int ni = 0; ni < 4; ni++)
                        acc[mi][ni] = __builtin_amdgcn_mfma_f32_16x16x32_bf16(
                            av[mi], bv[ni], acc[mi][ni], 0, 0, 0);
            }
            __syncthreads();
        }
    }

    // ---- epilogue: bias+ReLU, 1x1-head partial reduction over this wg's 128 channels
    float* shf = smemf;            // [64 cols][132]
    float* sW  = smemf + 8448;     // [128][20]
    for (int j = tid; j < 128*18; j += 256) {
        int c = j / 18, o = j - c*18;
        sW[c*20 + o] = (o < 6) ? w_cls[(size_t)(n0 + c)*6 + o]
                               : w_dlt[(size_t)(n0 + c)*12 + (o - 6)];
    }
    float bsh[4];
    #pragma unroll
    for (int ni = 0; ni < 4; ni++) bsh[ni] = b_sh[n0 + wc*64 + ni*16 + l15];

    float a18[18];
    #pragma unroll
    for (int o = 0; o < 18; o++) a18[o] = 0.f;
    const int rr = tid & 127, chalf = tid >> 7;

    #pragma unroll
    for (int pass = 0; pass < 2; pass++) {
        if (wc == pass) {
            #pragma unroll
            for (int mi = 0; mi < 4; mi++)
                #pragma unroll
                for (int ni = 0; ni < 4; ni++) {
                    int colL = ni*16 + l15;
                    int row0 = wr*64 + mi*16 + l4*4;
                    f32x4 v = acc[mi][ni];
                    f32x4 s;
                    #pragma unroll
                    for (int r = 0; r < 4; r++) s[r] = fmaxf(v[r] + bsh[ni], 0.f);
                    *(f32x4*)(shf + colL*132 + row0) = s;
                }
        }
        __syncthreads();
        #pragma unroll 4
        for (int i = 0; i < 32; i++) {
            int c = chalf*32 + i;
            float v = shf[c*132 + rr];
            const float* wrow = sW + (pass*64 + c)*20;   // channel = n0 + pass*64 + c
            #pragma unroll
            for (int o = 0; o < 18; o++) a18[o] += v * wrow[o];
        }
        __syncthreads();
    }

    const int pixel = mtile*128 + rr;
    if (USE_WS) {
        if (chalf == 1) {
            #pragma unroll
            for (int o = 0; o < 18; o++) shf[rr*18 + o] = a18[o];
        }
        __syncthreads();
        if (chalf == 0) {
            float* dst = part + ((size_t)ntile*NPIX + pixel)*18;
            #pragma unroll
            for (int o = 0; o < 18; o++) dst[o] = a18[o] + shf[rr*18 + o];
        }
    } else {
        float* lo = out + (size_t)pixel*6;
        float* dl = out + DELTA_BASE + (size_t)pixel*12;
        #pragma unroll
        for (int o = 0; o < 6; o++)  atomicAdd(lo + o, a18[o]);
        #pragma unroll
        for (int o = 0; o < 12; o++) atomicAdd(dl + o, a18[6 + o]);
    }
}

// ---- finalize (ws path): sum 4 partials, biases, softmax -> all outputs
__global__ __launch_bounds__(256) void k_finalize_ws(const float* __restrict__ part,
                                                     float* __restrict__ out,
                                                     const float* __restrict__ b_cls,
                                                     const float* __restrict__ b_dlt) {
    int pix = blockIdx.x*256 + threadIdx.x;
    if (pix >= NPIX) return;
    float s[18];
    #pragma unroll
    for (int o = 0; o < 18; o++) s[o] = 0.f;
    #pragma unroll
    for (int nt = 0; nt < 4; nt++) {
        const float* p = part + ((size_t)nt*NPIX + pix)*18;
        #pragma unroll
        for (int o = 0; o < 18; o++) s[o] += p[o];
    }
    float* lo = out + (size_t)pix*6;
    float* pr = out + (size_t)LOGITS_N + (size_t)pix*6;
    float* dl = out + (size_t)DELTA_BASE + (size_t)pix*12;
    #pragma unroll
    for (int a = 0; a < 3; a++) {
        float l0 = s[a*2]   + b_cls[a*2];
        float l1 = s[a*2+1] + b_cls[a*2+1];
        lo[a*2] = l0; lo[a*2+1] = l1;
        float m = fmaxf(l0, l1);
        float e0 = __expf(l0 - m), e1 = __expf(l1 - m);
        float inv = 1.f / (e0 + e1);
        pr[a*2] = e0*inv; pr[a*2+1] = e1*inv;
    }
    #pragma unroll
    for (int o = 0; o < 12; o++) dl[o] = s[6 + o] + b_dlt[o];
}

// ---- finalize (fallback path): logits already in out via atomics
__global__ __launch_bounds__(256) void k_finalize(float* __restrict__ out,
                                                  const float* __restrict__ b_cls,
                                                  const float* __restrict__ b_dlt) {
    int pix = blockIdx.x*256 + threadIdx.x;
    if (pix >= NPIX) return;
    float* lo = out + (size_t)pix*6;
    float* pr = out + (size_t)LOGITS_N + (size_t)pix*6;
    float* dl = out + (size_t)DELTA_BASE + (size_t)pix*12;
    #pragma unroll
    for (int a = 0; a < 3; a++) {
        float l0 = lo[a*2]   + b_cls[a*2];
        float l1 = lo[a*2+1] + b_cls[a*2+1];
        lo[a*2] = l0; lo[a*2+1] = l1;
        float m = fmaxf(l0, l1);
        float e0 = __expf(l0 - m), e1 = __expf(l1 - m);
        float inv = 1.f / (e0 + e1);
        pr[a*2] = e0*inv; pr[a*2+1] = e1*inv;
    }
    #pragma unroll
    for (int o = 0; o < 12; o++) dl[o] += b_dlt[o];
}

extern "C" void kernel_launch(void* const* d_in, const int* in_sizes, int n_in,
                              void* d_out, int out_size, void* d_ws, size_t ws_size,
                              hipStream_t stream) {
    const float* in    = (const float*)d_in[0];
    const float* w_sh  = (const float*)d_in[1];
    const float* b_sh  = (const float*)d_in[2];
    const float* w_cls = (const float*)d_in[3];
    const float* b_cls = (const float*)d_in[4];
    const float* w_dlt = (const float*)d_in[5];
    const float* b_dlt = (const float*)d_in[6];
    float* out = (float*)d_out;

    const size_t in_p_elems = (size_t)BATCH*HP*HP*CIN;   // 17,305,600
    const size_t wt_elems   = (size_t)9*CO*CIN;          // 1,179,648
    const size_t part_elems = (size_t)4*NPIX*18;         // 4,718,592
    const size_t need = (in_p_elems + wt_elems)*2 + part_elems*4;  // ~54.7 MB

    if (ws_size >= need) {
        unsigned short* in_p = (unsigned short*)d_ws;
        unsigned short* wt   = in_p + in_p_elems;
        float* part = (float*)(wt + wt_elems);
        int padq = (int)(((size_t)BATCH*HP*HP*64 + 255)/256);
        k_pad_convert<<<padq, 256, 0, stream>>>(in, in_p);
        k_wt_convert<<<9*CO, 256, 0, stream>>>(w_sh, wt);
        k_main<1><<<2048, 256, 0, stream>>>(in_p, wt, nullptr, nullptr,
                                            b_sh, w_cls, w_dlt, out, part);
        k_finalize_ws<<<(NPIX + 255)/256, 256, 0, stream>>>(part, out, b_cls, b_dlt);
    } else {
        hipMemsetAsync(d_out, 0, (size_t)out_size * sizeof(float), stream);
        k_main<0><<<2048, 256, 0, stream>>>(nullptr, nullptr, in, w_sh,
                                            b_sh, w_cls, w_dlt, out, nullptr);
        k_finalize<<<(NPIX + 255)/256, 256, 0, stream>>>(out, b_cls, b_dlt);
    }
}

// Round 5
// 218.055 us; speedup vs baseline: 2.2051x; 1.0202x over previous
//
#include <hip/hip_runtime.h>
#include <stdint.h>

#define BATCH 4
#define HH 128
#define WW 128
#define CIN 256
#define CO 512
#define HP 130
#define NPIX (BATCH*HH*WW)          // 65536
#define LOGITS_N (NPIX*6)           // 393216
#define DELTA_BASE (2*LOGITS_N)     // 786432

typedef short bf16x8 __attribute__((ext_vector_type(8)));
typedef unsigned short u16x8 __attribute__((ext_vector_type(8)));
typedef float f32x4 __attribute__((ext_vector_type(4)));
typedef unsigned int u32;

__device__ __forceinline__ unsigned short f2bf(float f) {
    union { float f; unsigned int u; } v; v.f = f;
    return (unsigned short)((v.u + 0x7FFFu + ((v.u >> 16) & 1u)) >> 16);
}

__device__ __forceinline__ void gload16(const unsigned short* g, char* l) {
    __builtin_amdgcn_global_load_lds(
        (const __attribute__((address_space(1))) u32*)g,
        (__attribute__((address_space(3))) u32*)l, 16, 0, 0);
}

// ---- pass 1a: fp32 input -> bf16 with 1-pixel zero halo: [B][130][130][256]
__global__ __launch_bounds__(256) void k_pad_convert(const float* __restrict__ in,
                                                     unsigned short* __restrict__ out) {
    size_t q = (size_t)blockIdx.x*256 + threadIdx.x;     // quad index (4 channels)
    if (q >= (size_t)BATCH*HP*HP*64) return;
    int c4 = ((int)q & 63) * 4;
    int pix = (int)(q >> 6);
    int xx = pix % HP; int t = pix / HP; int yy = t % HP; int b = t / HP;
    ushort4 r = {0, 0, 0, 0};
    if (yy >= 1 && yy <= HH && xx >= 1 && xx <= WW) {
        const float4 v = *(const float4*)(in + (((size_t)(b*HH) + (yy-1))*WW + (xx-1))*CIN + c4);
        r.x = f2bf(v.x); r.y = f2bf(v.y); r.z = f2bf(v.z); r.w = f2bf(v.w);
    }
    *(ushort4*)(out + (size_t)pix*CIN + c4) = r;
}

// ---- pass 1b: w_shared [9][256][512] fp32 -> wT [9][512][256] bf16
__global__ __launch_bounds__(256) void k_wt_convert(const float* __restrict__ w,
                                                    unsigned short* __restrict__ wt) {
    int n = blockIdx.x % CO; int tap = blockIdx.x / CO;
    int c = threadIdx.x;
    wt[((size_t)tap*CO + n)*CIN + c] = f2bf(w[((size_t)tap*CIN + c)*CO + n]);
}

// ============ main: 256x256 tile, 4-phase/K-step, counted-vmcnt pipeline ============
// M=65536 pixels, N=512 (2 tiles), K=2304 (9 taps x 4 kq, BK=64). 512 thr, 8 waves (2Mx4N).
// LDS: 2 bufs x [A 256x64 | B 256x64] bf16 = 128 KiB dynamic.
__global__ __launch_bounds__(512, 2) void k_main8(
    const unsigned short* __restrict__ in_p,   // bf16 padded input
    const unsigned short* __restrict__ wt,     // bf16 wT [9][512][256]
    const float* __restrict__ b_sh,
    const float* __restrict__ w_cls,
    const float* __restrict__ w_dlt,
    float* __restrict__ part)                  // [2][NPIX][18]
{
    extern __shared__ char LDS[];

    const int tid  = threadIdx.x;
    const int lane = tid & 63, wave = tid >> 6;
    const int l15  = lane & 15, l4 = lane >> 4;
    const int wm   = wave >> 2, wn = wave & 3;

    // XCD-contiguous bijective swizzle (512 % 8 == 0)
    const int bid   = ((blockIdx.x & 7) << 6) + (blockIdx.x >> 3);
    const int ntile = bid & 1, mtile = bid >> 1;
    const int n0 = ntile << 8;
    const int b  = mtile >> 6;
    const int y0 = (mtile & 63) * 2;           // tile covers image rows y0, y0+1

    // per-thread staging offset (same for A and B): chunk = tid -> row tid>>3, sub tid&7
    const int rl0 = tid >> 3, pc0 = tid & 7;
    const int kc0 = pc0 ^ (rl0 & 7);           // inverse XOR swizzle on SOURCE
    const int off = rl0*256 + kc0*8;           // elements
    const int t16 = tid*16;                    // linear LDS dest byte offset

    // MFMA fragment LDS byte offsets (swizzled reads); +mi*2048 / +ni*2048 folds to imm
    int base_a[2], base_b[2];
    #pragma unroll
    for (int kk = 0; kk < 2; kk++) {
        int swz = ((kk*32 + l4*8)*2) ^ ((l15 & 7) << 4);
        base_a[kk] = (wm*128 + l15)*128 + swz;
        base_b[kk] = 32768 + (wn*64 + l15)*128 + swz;
    }

    f32x4 acc[8][4];
    const f32x4 zz = {0.f, 0.f, 0.f, 0.f};
    #pragma unroll
    for (int mi = 0; mi < 8; mi++)
        #pragma unroll
        for (int ni = 0; ni < 4; ni++) acc[mi][ni] = zz;

    // ---- prologue: stage tile 0 (HT order: B-lo, B-hi, A-even64, A-odd64)
    {
        const unsigned short* gB0 = wt + (size_t)n0*256;
        const unsigned short* gA0 = in_p + ((size_t)(b*HP + y0))*HP*256;
        char* Ad0 = LDS; char* Bd0 = LDS + 32768;
        gload16(gB0 + off,          Bd0 + t16);           // HT0: B cols 0-63
        gload16(gB0 + 16384 + off,  Bd0 + 8192 + t16);    //      B cols 64-127
        gload16(gB0 + 32768 + off,  Bd0 + 16384 + t16);   // HT1: B cols 128-191
        gload16(gB0 + 49152 + off,  Bd0 + 24576 + t16);   //      B cols 192-255
        gload16(gA0 + off,          Ad0 + t16);           // HT2: A rows 0-63
        gload16(gA0 + 33280 + off,  Ad0 + 16384 + t16);   //      A rows 128-191
        gload16(gA0 + 16384 + off,  Ad0 + 8192 + t16);    // HT3: A rows 64-127
        gload16(gA0 + 49664 + off,  Ad0 + 24576 + t16);   //      A rows 192-255
    }
    asm volatile("s_waitcnt vmcnt(2)" ::: "memory");      // HT0-2 landed; HT3 may fly
    __builtin_amdgcn_sched_barrier(0);
    __builtin_amdgcn_s_barrier();
    __builtin_amdgcn_sched_barrier(0);

#define DS_PHASE(Q)                                                          \
    bf16x8 a_[2][2], b_[4][2];                                               \
    _Pragma("unroll")                                                        \
    for (int kk = 0; kk < 2; kk++) {                                         \
        a_[0][kk] = *(const bf16x8*)(bufc + base_a[kk] + (2*(Q))*2048);      \
        a_[1][kk] = *(const bf16x8*)(bufc + base_a[kk] + (2*(Q)+1)*2048);    \
        b_[0][kk] = *(const bf16x8*)(bufc + base_b[kk]);                     \
        b_[1][kk] = *(const bf16x8*)(bufc + base_b[kk] + 2048);              \
        b_[2][kk] = *(const bf16x8*)(bufc + base_b[kk] + 4096);              \
        b_[3][kk] = *(const bf16x8*)(bufc + base_b[kk] + 6144);              \
    }

#define MFMA_PHASE(Q)                                                        \
    __builtin_amdgcn_s_barrier();                                            \
    __builtin_amdgcn_sched_barrier(0);                                       \
    __builtin_amdgcn_s_setprio(1);                                           \
    _Pragma("unroll")                                                        \
    for (int mm = 0; mm < 2; mm++)                                           \
        _Pragma("unroll")                                                    \
        for (int ni = 0; ni < 4; ni++)                                       \
            _Pragma("unroll")                                                \
            for (int kk = 0; kk < 2; kk++)                                   \
                acc[2*(Q)+mm][ni] = __builtin_amdgcn_mfma_f32_16x16x32_bf16( \
                    a_[mm][kk], b_[ni][kk], acc[2*(Q)+mm][ni], 0, 0, 0);     \
    __builtin_amdgcn_s_setprio(0);

#define END_PHASE                                                            \
    __builtin_amdgcn_s_barrier();                                            \
    __builtin_amdgcn_sched_barrier(0);

    for (int s = 0; s < 36; ++s) {
        const int s1 = s + 1;
        const int tap1 = s1 >> 2, kq1 = s1 & 3;
        const int dy1 = (tap1*11) >> 5, dx1 = tap1 - dy1*3;
        const unsigned short* gA = in_p + ((size_t)((b*HP + y0 + dy1)*HP + dx1))*256 + kq1*64;
        const unsigned short* gB = wt + ((size_t)(tap1*512 + n0))*256 + kq1*64;
        const int cur = s & 1;
        const char* bufc = LDS + (cur << 16);
        char* Ad = LDS + ((cur ^ 1) << 16);
        char* Bd = Ad + 32768;
        const bool more = (s < 35);

        { // phase 0: stage HT0(s+1) = B cols 0-127
            DS_PHASE(0)
            if (more) { gload16(gB + off,         Bd + t16);
                        gload16(gB + 16384 + off, Bd + 8192 + t16); }
            MFMA_PHASE(0)
            END_PHASE
        }
        { // phase 1: stage HT1(s+1) = B cols 128-255; then guarantee HT3(s)
            DS_PHASE(1)
            if (more) { gload16(gB + 32768 + off, Bd + 16384 + t16);
                        gload16(gB + 49152 + off, Bd + 24576 + t16); }
            MFMA_PHASE(1)
            if (more) { asm volatile("s_waitcnt vmcnt(4)" ::: "memory"); }
            else      { asm volatile("s_waitcnt vmcnt(0)" ::: "memory"); }
            __builtin_amdgcn_sched_barrier(0);
            END_PHASE
        }
        { // phase 2: stage HT2(s+1) = A rows 0-63,128-191 (uses HT3(s) data)
            DS_PHASE(2)
            if (more) { gload16(gA + off,         Ad + t16);
                        gload16(gA + 33280 + off, Ad + 16384 + t16); }
            MFMA_PHASE(2)
            END_PHASE
        }
        { // phase 3: stage HT3(s+1) = A rows 64-127,192-255; guarantee HT0-2(s+1)
            DS_PHASE(3)
            if (more) { gload16(gA + 16384 + off, Ad + 8192 + t16);
                        gload16(gA + 49664 + off, Ad + 24576 + t16); }
            MFMA_PHASE(3)
            if (more) { asm volatile("s_waitcnt vmcnt(2)" ::: "memory");
                        __builtin_amdgcn_sched_barrier(0); }
            END_PHASE
        }
    }
#undef DS_PHASE
#undef MFMA_PHASE
#undef END_PHASE

    // ---- epilogue: bias+ReLU + 1x1-head partial reduction over this block's 256 channels
    float* shf = (float*)LDS;                  // [64 cols][260]
    float* sW  = (float*)(LDS + 66560);        // [256][20]
    for (int j = tid; j < 256*18; j += 512) {
        int c = j / 18, o = j - c*18;
        sW[c*20 + o] = (o < 6) ? w_cls[(size_t)(n0 + c)*6 + o]
                               : w_dlt[(size_t)(n0 + c)*12 + (o - 6)];
    }
    float bsh[4];
    #pragma unroll
    for (int ni = 0; ni < 4; ni++) bsh[ni] = b_sh[n0 + wn*64 + ni*16 + l15];

    float a18[18];
    #pragma unroll
    for (int o = 0; o < 18; o++) a18[o] = 0.f;
    const int rr = tid & 255, chalf = tid >> 8;
    __syncthreads();

    for (int p = 0; p < 4; ++p) {
        if (wn == p) {
            #pragma unroll
            for (int mi = 0; mi < 8; mi++)
                #pragma unroll
                for (int ni = 0; ni < 4; ni++) {
                    int colL = ni*16 + l15;
                    int row0 = wm*128 + mi*16 + l4*4;
                    f32x4 v = acc[mi][ni];
                    f32x4 sv;
                    #pragma unroll
                    for (int r = 0; r < 4; r++) sv[r] = fmaxf(v[r] + bsh[ni], 0.f);
                    *(f32x4*)(shf + colL*260 + row0) = sv;
                }
        }
        __syncthreads();
        #pragma unroll 4
        for (int i = 0; i < 32; i++) {
            int c = chalf*32 + i;
            float v = shf[c*260 + rr];
            const float* wrow = sW + (p*64 + c)*20;
            #pragma unroll
            for (int o = 0; o < 18; o++) a18[o] += v * wrow[o];
        }
        __syncthreads();
    }

    if (chalf == 1) {
        #pragma unroll
        for (int o = 0; o < 18; o++) shf[rr*18 + o] = a18[o];
    }
    __syncthreads();
    if (chalf == 0) {
        float* dst = part + ((size_t)ntile*NPIX + (size_t)mtile*256 + rr)*18;
        #pragma unroll
        for (int o = 0; o < 18; o++) dst[o] = a18[o] + shf[rr*18 + o];
    }
}

// ---- finalize (ws path): sum 2 partials, biases, softmax -> all outputs
__global__ __launch_bounds__(256) void k_finalize_ws(const float* __restrict__ part,
                                                     float* __restrict__ out,
                                                     const float* __restrict__ b_cls,
                                                     const float* __restrict__ b_dlt) {
    int pix = blockIdx.x*256 + threadIdx.x;
    if (pix >= NPIX) return;
    float s[18];
    #pragma unroll
    for (int o = 0; o < 18; o++)
        s[o] = part[(size_t)pix*18 + o] + part[((size_t)NPIX + pix)*18 + o];
    float* lo = out + (size_t)pix*6;
    float* pr = out + (size_t)LOGITS_N + (size_t)pix*6;
    float* dl = out + (size_t)DELTA_BASE + (size_t)pix*12;
    #pragma unroll
    for (int a = 0; a < 3; a++) {
        float l0 = s[a*2]   + b_cls[a*2];
        float l1 = s[a*2+1] + b_cls[a*2+1];
        lo[a*2] = l0; lo[a*2+1] = l1;
        float m = fmaxf(l0, l1);
        float e0 = __expf(l0 - m), e1 = __expf(l1 - m);
        float inv = 1.f / (e0 + e1);
        pr[a*2] = e0*inv; pr[a*2+1] = e1*inv;
    }
    #pragma unroll
    for (int o = 0; o < 12; o++) dl[o] = s[6 + o] + b_dlt[o];
}

// ======== fallback path (no workspace): round-2 proven kernel, atomics ========
__global__ __launch_bounds__(256) void k_main_fb(
    const float* __restrict__ in_f, const float* __restrict__ w_f,
    const float* __restrict__ b_sh, const float* __restrict__ w_cls,
    const float* __restrict__ w_dlt, float* __restrict__ out)
{
    __shared__ float smemf[11008];
    char* smem  = (char*)smemf;
    char* smemB = smem + 16384;
    const int tid = threadIdx.x;
    const int lane = tid & 63, wave = tid >> 6;
    const int l15 = lane & 15, l4 = lane >> 4;
    const int wr = wave >> 1, wc = wave & 1;
    int bid = ((blockIdx.x & 7) << 8) + (blockIdx.x >> 3);
    const int ntile = bid & 3, mtile = bid >> 2;
    const int n0 = ntile << 7;
    const int b = mtile >> 7, y = mtile & 127;
    int aoff[4][2], boff[4][2];
    #pragma unroll
    for (int mi = 0; mi < 4; mi++) {
        int rowA = wr*64 + mi*16 + l15;
        int rowB = wc*64 + mi*16 + l15;
        #pragma unroll
        for (int kk = 0; kk < 2; kk++) {
            int kb = (kk*32 + l4*8) * 2;
            aoff[mi][kk] = rowA*128 + (kb ^ ((rowA & 7) << 4));
            boff[mi][kk] = rowB*128 + (kb ^ ((rowB & 7) << 4));
        }
    }
    f32x4 acc[4][4];
    const f32x4 zz = {0.f, 0.f, 0.f, 0.f};
    #pragma unroll
    for (int mi = 0; mi < 4; mi++)
        #pragma unroll
        for (int ni = 0; ni < 4; ni++) acc[mi][ni] = zz;
    for (int s = 0; s < 36; s++) {
        int tap = s >> 2, kq = s & 3;
        int dy = tap / 3, dx = tap - dy*3;
        const int c0 = kq * 64;
        const int yy = y + dy - 1;
        const bool yok = (yy >= 0) && (yy < HH);
        #pragma unroll
        for (int i = 0; i < 4; i++) {
            int ci = i*256 + tid;
            int row = ci >> 3, pc = ci & 7;
            int kc = pc ^ (row & 7);
            int xx = row + dx - 1;
            u16x8 a;
            if (yok && xx >= 0 && xx < WW) {
                const float* sp = in_f + (((size_t)(b*HH) + yy)*WW + xx)*CIN + c0 + kc*8;
                #pragma unroll
                for (int j = 0; j < 8; j++) a[j] = (short)f2bf(sp[j]);
            } else {
                #pragma unroll
                for (int j = 0; j < 8; j++) a[j] = 0;
            }
            *(u16x8*)(smem + ci*16) = a;
            const float* wsrc = w_f + ((size_t)(tap*CIN + c0 + kc*8))*CO + n0 + row;
            u16x8 bb;
            #pragma unroll
            for (int j = 0; j < 8; j++) bb[j] = (short)f2bf(wsrc[(size_t)j*CO]);
            *(u16x8*)(smemB + ci*16) = bb;
        }
        __syncthreads();
        #pragma unroll
        for (int kk = 0; kk < 2; kk++) {
            bf16x8 av[4], bv[4];
            #pragma unroll
            for (int mi = 0; mi < 4; mi++) av[mi] = *(const bf16x8*)(smem  + aoff[mi][kk]);
            #pragma unroll
            for (int ni = 0; ni < 4; ni++) bv[ni] = *(const bf16x8*)(smemB + boff[ni][kk]);
            #pragma unroll
            for (int mi = 0; mi < 4; mi++)
                #pragma unroll
                for (int ni = 0; ni < 4; ni++)
                    acc[mi][ni] = __builtin_amdgcn_mfma_f32_16x16x32_bf16(
                        av[mi], bv[ni], acc[mi][ni], 0, 0, 0);
        }
        __syncthreads();
    }
    float* shf = smemf;
    float* sW  = smemf + 8448;
    for (int j = tid; j < 128*18; j += 256) {
        int c = j / 18, o = j - c*18;
        sW[c*20 + o] = (o < 6) ? w_cls[(size_t)(n0 + c)*6 + o]
                               : w_dlt[(size_t)(n0 + c)*12 + (o - 6)];
    }
    float bsh[4];
    #pragma unroll
    for (int ni = 0; ni < 4; ni++) bsh[ni] = b_sh[n0 + wc*64 + ni*16 + l15];
    float a18[18];
    #pragma unroll
    for (int o = 0; o < 18; o++) a18[o] = 0.f;
    const int rr = tid & 127, chalf = tid >> 7;
    #pragma unroll
    for (int pass = 0; pass < 2; pass++) {
        if (wc == pass) {
            #pragma unroll
            for (int mi = 0; mi < 4; mi++)
                #pragma unroll
                for (int ni = 0; ni < 4; ni++) {
                    int colL = ni*16 + l15;
                    int row0 = wr*64 + mi*16 + l4*4;
                    f32x4 v = acc[mi][ni];
                    f32x4 sv;
                    #pragma unroll
                    for (int r = 0; r < 4; r++) sv[r] = fmaxf(v[r] + bsh[ni], 0.f);
                    *(f32x4*)(shf + colL*132 + row0) = sv;
                }
        }
        __syncthreads();
        #pragma unroll 4
        for (int i = 0; i < 32; i++) {
            int c = chalf*32 + i;
            float v = shf[c*132 + rr];
            const float* wrow = sW + (pass*64 + c)*20;
            #pragma unroll
            for (int o = 0; o < 18; o++) a18[o] += v * wrow[o];
        }
        __syncthreads();
    }
    const int pixel = mtile*128 + rr;
    float* lo = out + (size_t)pixel*6;
    float* dl = out + DELTA_BASE + (size_t)pixel*12;
    #pragma unroll
    for (int o = 0; o < 6; o++)  atomicAdd(lo + o, a18[o]);
    #pragma unroll
    for (int o = 0; o < 12; o++) atomicAdd(dl + o, a18[6 + o]);
}

__global__ __launch_bounds__(256) void k_finalize(float* __restrict__ out,
                                                  const float* __restrict__ b_cls,
                                                  const float* __restrict__ b_dlt) {
    int pix = blockIdx.x*256 + threadIdx.x;
    if (pix >= NPIX) return;
    float* lo = out + (size_t)pix*6;
    float* pr = out + (size_t)LOGITS_N + (size_t)pix*6;
    float* dl = out + (size_t)DELTA_BASE + (size_t)pix*12;
    #pragma unroll
    for (int a = 0; a < 3; a++) {
        float l0 = lo[a*2]   + b_cls[a*2];
        float l1 = lo[a*2+1] + b_cls[a*2+1];
        lo[a*2] = l0; lo[a*2+1] = l1;
        float m = fmaxf(l0, l1);
        float e0 = __expf(l0 - m), e1 = __expf(l1 - m);
        float inv = 1.f / (e0 + e1);
        pr[a*2] = e0*inv; pr[a*2+1] = e1*inv;
    }
    #pragma unroll
    for (int o = 0; o < 12; o++) dl[o] += b_dlt[o];
}

extern "C" void kernel_launch(void* const* d_in, const int* in_sizes, int n_in,
                              void* d_out, int out_size, void* d_ws, size_t ws_size,
                              hipStream_t stream) {
    const float* in    = (const float*)d_in[0];
    const float* w_sh  = (const float*)d_in[1];
    const float* b_sh  = (const float*)d_in[2];
    const float* w_cls = (const float*)d_in[3];
    const float* b_cls = (const float*)d_in[4];
    const float* w_dlt = (const float*)d_in[5];
    const float* b_dlt = (const float*)d_in[6];
    float* out = (float*)d_out;

    const size_t in_p_elems = (size_t)BATCH*HP*HP*CIN;   // 17,305,600
    const size_t wt_elems   = (size_t)9*CO*CIN;          // 1,179,648
    const size_t part_elems = (size_t)2*NPIX*18;         // 2,359,296
    const size_t need = (in_p_elems + wt_elems)*2 + part_elems*4;  // ~46.4 MB

    if (ws_size >= need) {
        unsigned short* in_p = (unsigned short*)d_ws;
        unsigned short* wt   = in_p + in_p_elems;
        float* part = (float*)(wt + wt_elems);
        hipFuncSetAttribute((const void*)k_main8,
                            hipFuncAttributeMaxDynamicSharedMemorySize, 131072);
        int padq = (int)(((size_t)BATCH*HP*HP*64 + 255)/256);
        k_pad_convert<<<padq, 256, 0, stream>>>(in, in_p);
        k_wt_convert<<<9*CO, 256, 0, stream>>>(w_sh, wt);
        k_main8<<<512, 512, 131072, stream>>>(in_p, wt, b_sh, w_cls, w_dlt, part);
        k_finalize_ws<<<(NPIX + 255)/256, 256, 0, stream>>>(part, out, b_cls, b_dlt);
    } else {
        hipMemsetAsync(d_out, 0, (size_t)out_size * sizeof(float), stream);
        k_main_fb<<<2048, 256, 0, stream>>>(in, w_sh, b_sh, w_cls, w_dlt, out);
        k_finalize<<<(NPIX + 255)/256, 256, 0, stream>>>(out, b_cls, b_dlt);
    }
}

// Round 6
// 200.002 us; speedup vs baseline: 2.4041x; 1.0903x over previous
//
#include <hip/hip_runtime.h>
#include <stdint.h>

#define BATCH 4
#define HH 128
#define WW 128
#define CIN 256
#define CO 512
#define HP 130
#define NPIX (BATCH*HH*WW)          // 65536
#define LOGITS_N (NPIX*6)           // 393216
#define DELTA_BASE (2*LOGITS_N)     // 786432

typedef short bf16x8 __attribute__((ext_vector_type(8)));
typedef unsigned short u16x8 __attribute__((ext_vector_type(8)));
typedef float f32x4 __attribute__((ext_vector_type(4)));
typedef unsigned int u32;

__device__ __forceinline__ unsigned short f2bf(float f) {
    union { float f; unsigned int u; } v; v.f = f;
    return (unsigned short)((v.u + 0x7FFFu + ((v.u >> 16) & 1u)) >> 16);
}

__device__ __forceinline__ void gload16(const unsigned short* g, char* l) {
    __builtin_amdgcn_global_load_lds(
        (const __attribute__((address_space(1))) u32*)g,
        (__attribute__((address_space(3))) u32*)l, 16, 0, 0);
}

// ---- pass 1a: fp32 input -> bf16 with 1-pixel zero halo: [B][130][130][256]
__global__ __launch_bounds__(256) void k_pad_convert(const float* __restrict__ in,
                                                     unsigned short* __restrict__ out) {
    size_t q = (size_t)blockIdx.x*256 + threadIdx.x;     // quad index (4 channels)
    if (q >= (size_t)BATCH*HP*HP*64) return;
    int c4 = ((int)q & 63) * 4;
    int pix = (int)(q >> 6);
    int xx = pix % HP; int t = pix / HP; int yy = t % HP; int b = t / HP;
    ushort4 r = {0, 0, 0, 0};
    if (yy >= 1 && yy <= HH && xx >= 1 && xx <= WW) {
        const float4 v = *(const float4*)(in + (((size_t)(b*HH) + (yy-1))*WW + (xx-1))*CIN + c4);
        r.x = f2bf(v.x); r.y = f2bf(v.y); r.z = f2bf(v.z); r.w = f2bf(v.w);
    }
    *(ushort4*)(out + (size_t)pix*CIN + c4) = r;
}

// ---- pass 1b: w_shared [9][256][512] fp32 -> wT [9][512][256] bf16
__global__ __launch_bounds__(256) void k_wt_convert(const float* __restrict__ w,
                                                    unsigned short* __restrict__ wt) {
    int n = blockIdx.x % CO; int tap = blockIdx.x / CO;
    int c = threadIdx.x;
    wt[((size_t)tap*CO + n)*CIN + c] = f2bf(w[((size_t)tap*CIN + c)*CO + n]);
}

// ============ main: 256x256 tile, 4-phase/K-step, counted-vmcnt pipeline ============
// M=65536 pixels, N=512 (2 tiles), K=2304 (9 taps x 4 kq, BK=64). 512 thr, 8 waves (2Mx4N).
// LDS: 2 bufs x [A 256x64 | B 256x64] bf16 = 128 KiB dynamic.
// B fragments loaded ONCE per K-step into registers (phase 0); phases read only A quads.
__global__ __launch_bounds__(512, 2) void k_main8(
    const unsigned short* __restrict__ in_p,   // bf16 padded input
    const unsigned short* __restrict__ wt,     // bf16 wT [9][512][256]
    const float* __restrict__ b_sh,
    const float* __restrict__ w_cls,
    const float* __restrict__ w_dlt,
    float* __restrict__ part)                  // [2][NPIX][18]
{
    extern __shared__ char LDS[];

    const int tid  = threadIdx.x;
    const int lane = tid & 63, wave = tid >> 6;
    const int l15  = lane & 15, l4 = lane >> 4;
    const int wm   = wave >> 2, wn = wave & 3;

    // XCD-contiguous bijective swizzle (512 % 8 == 0)
    const int bid   = ((blockIdx.x & 7) << 6) + (blockIdx.x >> 3);
    const int ntile = bid & 1, mtile = bid >> 1;
    const int n0 = ntile << 8;
    const int b  = mtile >> 6;
    const int y0 = (mtile & 63) * 2;           // tile covers image rows y0, y0+1

    // per-thread staging offset (same for A and B): chunk = tid -> row tid>>3, sub tid&7
    const int rl0 = tid >> 3, pc0 = tid & 7;
    const int kc0 = pc0 ^ (rl0 & 7);           // inverse XOR swizzle on SOURCE
    const int off = rl0*256 + kc0*8;           // elements
    const int t16 = tid*16;                    // linear LDS dest byte offset

    // MFMA fragment LDS byte offsets (swizzled reads); +mi*2048 / +ni*2048 folds to imm
    int base_a[2], base_b[2];
    #pragma unroll
    for (int kk = 0; kk < 2; kk++) {
        int swz = ((kk*32 + l4*8)*2) ^ ((l15 & 7) << 4);
        base_a[kk] = (wm*128 + l15)*128 + swz;
        base_b[kk] = 32768 + (wn*64 + l15)*128 + swz;
    }

    f32x4 acc[8][4];
    const f32x4 zz = {0.f, 0.f, 0.f, 0.f};
    #pragma unroll
    for (int mi = 0; mi < 8; mi++)
        #pragma unroll
        for (int ni = 0; ni < 4; ni++) acc[mi][ni] = zz;

    // ---- prologue: stage tile 0 (HT order: B-lo, B-hi, A-ht2, A-ht3)
    {
        const unsigned short* gB0 = wt + (size_t)n0*256;
        const unsigned short* gA0 = in_p + ((size_t)(b*HP + y0))*HP*256;
        char* Ad0 = LDS; char* Bd0 = LDS + 32768;
        gload16(gB0 + off,          Bd0 + t16);           // HT0: B cols 0-63
        gload16(gB0 + 16384 + off,  Bd0 + 8192 + t16);    //      B cols 64-127
        gload16(gB0 + 32768 + off,  Bd0 + 16384 + t16);   // HT1: B cols 128-191
        gload16(gB0 + 49152 + off,  Bd0 + 24576 + t16);   //      B cols 192-255
        gload16(gA0 + off,          Ad0 + t16);           // HT2: A rows 0-63
        gload16(gA0 + 33280 + off,  Ad0 + 16384 + t16);   //      A rows 128-191
        gload16(gA0 + 16384 + off,  Ad0 + 8192 + t16);    // HT3: A rows 64-127
        gload16(gA0 + 49664 + off,  Ad0 + 24576 + t16);   //      A rows 192-255
    }
    asm volatile("s_waitcnt vmcnt(2)" ::: "memory");      // HT0-2 landed; HT3 may fly
    __builtin_amdgcn_sched_barrier(0);
    __builtin_amdgcn_s_barrier();
    __builtin_amdgcn_sched_barrier(0);

#define MFMA16(Q)                                                            \
    __builtin_amdgcn_s_setprio(1);                                           \
    _Pragma("unroll")                                                        \
    for (int kk = 0; kk < 2; kk++)                                           \
        _Pragma("unroll")                                                    \
        for (int mm = 0; mm < 2; mm++)                                       \
            _Pragma("unroll")                                                \
            for (int ni = 0; ni < 4; ni++)                                   \
                acc[2*(Q)+mm][ni] = __builtin_amdgcn_mfma_f32_16x16x32_bf16( \
                    a_[mm][kk], breg[ni][kk], acc[2*(Q)+mm][ni], 0, 0, 0);   \
    __builtin_amdgcn_s_setprio(0);

#define BAR       __builtin_amdgcn_s_barrier(); __builtin_amdgcn_sched_barrier(0);
#define LOAD_AQ(Q)                                                           \
    bf16x8 a_[2][2];                                                         \
    _Pragma("unroll")                                                        \
    for (int kk = 0; kk < 2; kk++) {                                         \
        a_[0][kk] = *(const bf16x8*)(bufc + base_a[kk] + (2*(Q))*2048);      \
        a_[1][kk] = *(const bf16x8*)(bufc + base_a[kk] + (2*(Q)+1)*2048);    \
    }

    for (int s = 0; s < 36; ++s) {
        const int s1 = s + 1;
        const int tap1 = s1 >> 2, kq1 = s1 & 3;
        const int dy1 = (tap1*11) >> 5, dx1 = tap1 - dy1*3;
        const unsigned short* gA = in_p + ((size_t)((b*HP + y0 + dy1)*HP + dx1))*256 + kq1*64;
        const unsigned short* gB = wt + ((size_t)(tap1*512 + n0))*256 + kq1*64;
        const int cur = s & 1;
        const char* bufc = LDS + (cur << 16);
        char* Ad = LDS + ((cur ^ 1) << 16);
        char* Bd = Ad + 32768;
        const bool more = (s < 35);

        bf16x8 breg[4][2];                     // B for the whole K-step (read once)

        { // phase 0: load ALL B (8 reads) + A-quad0 (4 reads); stage HT0(s+1)
            bf16x8 a_[2][2];
            #pragma unroll
            for (int kk = 0; kk < 2; kk++) {
                a_[0][kk]  = *(const bf16x8*)(bufc + base_a[kk]);
                a_[1][kk]  = *(const bf16x8*)(bufc + base_a[kk] + 2048);
                breg[0][kk] = *(const bf16x8*)(bufc + base_b[kk]);
                breg[1][kk] = *(const bf16x8*)(bufc + base_b[kk] + 2048);
                breg[2][kk] = *(const bf16x8*)(bufc + base_b[kk] + 4096);
                breg[3][kk] = *(const bf16x8*)(bufc + base_b[kk] + 6144);
            }
            if (more) { gload16(gB + off,         Bd + t16);
                        gload16(gB + 16384 + off, Bd + 8192 + t16); }
            BAR
            MFMA16(0)
            BAR
        }
        { // phase 1: A-quad1; stage HT1(s+1); then guarantee HT3(s) for phases 2-3
            LOAD_AQ(1)
            if (more) { gload16(gB + 32768 + off, Bd + 16384 + t16);
                        gload16(gB + 49152 + off, Bd + 24576 + t16); }
            BAR
            MFMA16(1)
            if (more) { asm volatile("s_waitcnt vmcnt(4)" ::: "memory"); }
            else      { asm volatile("s_waitcnt vmcnt(0)" ::: "memory"); }
            __builtin_amdgcn_sched_barrier(0);
            BAR
        }
        { // phase 2: A-quad2 (HT3 rows); stage HT2(s+1)
            LOAD_AQ(2)
            if (more) { gload16(gA + off,         Ad + t16);
                        gload16(gA + 33280 + off, Ad + 16384 + t16); }
            BAR
            MFMA16(2)
            BAR
        }
        { // phase 3: A-quad3; stage HT3(s+1); guarantee HT0-2(s+1)
            LOAD_AQ(3)
            if (more) { gload16(gA + 16384 + off, Ad + 8192 + t16);
                        gload16(gA + 49664 + off, Ad + 24576 + t16); }
            BAR
            MFMA16(3)
            if (more) { asm volatile("s_waitcnt vmcnt(2)" ::: "memory");
                        __builtin_amdgcn_sched_barrier(0); }
            BAR
        }
    }
#undef MFMA16
#undef BAR
#undef LOAD_AQ

    // ---- epilogue: bias+ReLU + 1x1-head partial reduction over this block's 256 channels
    float* shf = (float*)LDS;                  // [64 cols][260]
    float* sW  = (float*)(LDS + 66560);        // [256][20]
    for (int j = tid; j < 256*18; j += 512) {
        int c = j / 18, o = j - c*18;
        sW[c*20 + o] = (o < 6) ? w_cls[(size_t)(n0 + c)*6 + o]
                               : w_dlt[(size_t)(n0 + c)*12 + (o - 6)];
    }
    float bsh[4];
    #pragma unroll
    for (int ni = 0; ni < 4; ni++) bsh[ni] = b_sh[n0 + wn*64 + ni*16 + l15];

    float a18[18];
    #pragma unroll
    for (int o = 0; o < 18; o++) a18[o] = 0.f;
    const int rr = tid & 255, chalf = tid >> 8;
    __syncthreads();

    for (int p = 0; p < 4; ++p) {
        if (wn == p) {
            #pragma unroll
            for (int mi = 0; mi < 8; mi++)
                #pragma unroll
                for (int ni = 0; ni < 4; ni++) {
                    int colL = ni*16 + l15;
                    int row0 = wm*128 + mi*16 + l4*4;
                    f32x4 v = acc[mi][ni];
                    f32x4 sv;
                    #pragma unroll
                    for (int r = 0; r < 4; r++) sv[r] = fmaxf(v[r] + bsh[ni], 0.f);
                    *(f32x4*)(shf + colL*260 + row0) = sv;
                }
        }
        __syncthreads();
        #pragma unroll 4
        for (int i = 0; i < 32; i++) {
            int c = chalf*32 + i;
            float v = shf[c*260 + rr];
            const float* wrow = sW + (p*64 + c)*20;
            #pragma unroll
            for (int o = 0; o < 18; o++) a18[o] += v * wrow[o];
        }
        __syncthreads();
    }

    if (chalf == 1) {
        #pragma unroll
        for (int o = 0; o < 18; o++) shf[rr*18 + o] = a18[o];
    }
    __syncthreads();
    if (chalf == 0) {
        float* dst = part + ((size_t)ntile*NPIX + (size_t)mtile*256 + rr)*18;
        #pragma unroll
        for (int o = 0; o < 18; o++) dst[o] = a18[o] + shf[rr*18 + o];
    }
}

// ---- finalize (ws path): sum 2 partials, biases, softmax -> all outputs
__global__ __launch_bounds__(256) void k_finalize_ws(const float* __restrict__ part,
                                                     float* __restrict__ out,
                                                     const float* __restrict__ b_cls,
                                                     const float* __restrict__ b_dlt) {
    int pix = blockIdx.x*256 + threadIdx.x;
    if (pix >= NPIX) return;
    float s[18];
    #pragma unroll
    for (int o = 0; o < 18; o++)
        s[o] = part[(size_t)pix*18 + o] + part[((size_t)NPIX + pix)*18 + o];
    float* lo = out + (size_t)pix*6;
    float* pr = out + (size_t)LOGITS_N + (size_t)pix*6;
    float* dl = out + (size_t)DELTA_BASE + (size_t)pix*12;
    #pragma unroll
    for (int a = 0; a < 3; a++) {
        float l0 = s[a*2]   + b_cls[a*2];
        float l1 = s[a*2+1] + b_cls[a*2+1];
        lo[a*2] = l0; lo[a*2+1] = l1;
        float m = fmaxf(l0, l1);
        float e0 = __expf(l0 - m), e1 = __expf(l1 - m);
        float inv = 1.f / (e0 + e1);
        pr[a*2] = e0*inv; pr[a*2+1] = e1*inv;
    }
    #pragma unroll
    for (int o = 0; o < 12; o++) dl[o] = s[6 + o] + b_dlt[o];
}

// ======== fallback path (no workspace): round-2 proven kernel, atomics ========
__global__ __launch_bounds__(256) void k_main_fb(
    const float* __restrict__ in_f, const float* __restrict__ w_f,
    const float* __restrict__ b_sh, const float* __restrict__ w_cls,
    const float* __restrict__ w_dlt, float* __restrict__ out)
{
    __shared__ float smemf[11008];
    char* smem  = (char*)smemf;
    char* smemB = smem + 16384;
    const int tid = threadIdx.x;
    const int lane = tid & 63, wave = tid >> 6;
    const int l15 = lane & 15, l4 = lane >> 4;
    const int wr = wave >> 1, wc = wave & 1;
    int bid = ((blockIdx.x & 7) << 8) + (blockIdx.x >> 3);
    const int ntile = bid & 3, mtile = bid >> 2;
    const int n0 = ntile << 7;
    const int b = mtile >> 7, y = mtile & 127;
    int aoff[4][2], boff[4][2];
    #pragma unroll
    for (int mi = 0; mi < 4; mi++) {
        int rowA = wr*64 + mi*16 + l15;
        int rowB = wc*64 + mi*16 + l15;
        #pragma unroll
        for (int kk = 0; kk < 2; kk++) {
            int kb = (kk*32 + l4*8) * 2;
            aoff[mi][kk] = rowA*128 + (kb ^ ((rowA & 7) << 4));
            boff[mi][kk] = rowB*128 + (kb ^ ((rowB & 7) << 4));
        }
    }
    f32x4 acc[4][4];
    const f32x4 zz = {0.f, 0.f, 0.f, 0.f};
    #pragma unroll
    for (int mi = 0; mi < 4; mi++)
        #pragma unroll
        for (int ni = 0; ni < 4; ni++) acc[mi][ni] = zz;
    for (int s = 0; s < 36; s++) {
        int tap = s >> 2, kq = s & 3;
        int dy = tap / 3, dx = tap - dy*3;
        const int c0 = kq * 64;
        const int yy = y + dy - 1;
        const bool yok = (yy >= 0) && (yy < HH);
        #pragma unroll
        for (int i = 0; i < 4; i++) {
            int ci = i*256 + tid;
            int row = ci >> 3, pc = ci & 7;
            int kc = pc ^ (row & 7);
            int xx = row + dx - 1;
            u16x8 a;
            if (yok && xx >= 0 && xx < WW) {
                const float* sp = in_f + (((size_t)(b*HH) + yy)*WW + xx)*CIN + c0 + kc*8;
                #pragma unroll
                for (int j = 0; j < 8; j++) a[j] = (short)f2bf(sp[j]);
            } else {
                #pragma unroll
                for (int j = 0; j < 8; j++) a[j] = 0;
            }
            *(u16x8*)(smem + ci*16) = a;
            const float* wsrc = w_f + ((size_t)(tap*CIN + c0 + kc*8))*CO + n0 + row;
            u16x8 bb;
            #pragma unroll
            for (int j = 0; j < 8; j++) bb[j] = (short)f2bf(wsrc[(size_t)j*CO]);
            *(u16x8*)(smemB + ci*16) = bb;
        }
        __syncthreads();
        #pragma unroll
        for (int kk = 0; kk < 2; kk++) {
            bf16x8 av[4], bv[4];
            #pragma unroll
            for (int mi = 0; mi < 4; mi++) av[mi] = *(const bf16x8*)(smem  + aoff[mi][kk]);
            #pragma unroll
            for (int ni = 0; ni < 4; ni++) bv[ni] = *(const bf16x8*)(smemB + boff[ni][kk]);
            #pragma unroll
            for (int mi = 0; mi < 4; mi++)
                #pragma unroll
                for (int ni = 0; ni < 4; ni++)
                    acc[mi][ni] = __builtin_amdgcn_mfma_f32_16x16x32_bf16(
                        av[mi], bv[ni], acc[mi][ni], 0, 0, 0);
        }
        __syncthreads();
    }
    float* shf = smemf;
    float* sW  = smemf + 8448;
    for (int j = tid; j < 128*18; j += 256) {
        int c = j / 18, o = j - c*18;
        sW[c*20 + o] = (o < 6) ? w_cls[(size_t)(n0 + c)*6 + o]
                               : w_dlt[(size_t)(n0 + c)*12 + (o - 6)];
    }
    float bsh[4];
    #pragma unroll
    for (int ni = 0; ni < 4; ni++) bsh[ni] = b_sh[n0 + wc*64 + ni*16 + l15];
    float a18[18];
    #pragma unroll
    for (int o = 0; o < 18; o++) a18[o] = 0.f;
    const int rr = tid & 127, chalf = tid >> 7;
    #pragma unroll
    for (int pass = 0; pass < 2; pass++) {
        if (wc == pass) {
            #pragma unroll
            for (int mi = 0; mi < 4; mi++)
                #pragma unroll
                for (int ni = 0; ni < 4; ni++) {
                    int colL = ni*16 + l15;
                    int row0 = wr*64 + mi*16 + l4*4;
                    f32x4 v = acc[mi][ni];
                    f32x4 sv;
                    #pragma unroll
                    for (int r = 0; r < 4; r++) sv[r] = fmaxf(v[r] + bsh[ni], 0.f);
                    *(f32x4*)(shf + colL*132 + row0) = sv;
                }
        }
        __syncthreads();
        #pragma unroll 4
        for (int i = 0; i < 32; i++) {
            int c = chalf*32 + i;
            float v = shf[c*132 + rr];
            const float* wrow = sW + (pass*64 + c)*20;
            #pragma unroll
            for (int o = 0; o < 18; o++) a18[o] += v * wrow[o];
        }
        __syncthreads();
    }
    const int pixel = mtile*128 + rr;
    float* lo = out + (size_t)pixel*6;
    float* dl = out + DELTA_BASE + (size_t)pixel*12;
    #pragma unroll
    for (int o = 0; o < 6; o++)  atomicAdd(lo + o, a18[o]);
    #pragma unroll
    for (int o = 0; o < 12; o++) atomicAdd(dl + o, a18[6 + o]);
}

__global__ __launch_bounds__(256) void k_finalize(float* __restrict__ out,
                                                  const float* __restrict__ b_cls,
                                                  const float* __restrict__ b_dlt) {
    int pix = blockIdx.x*256 + threadIdx.x;
    if (pix >= NPIX) return;
    float* lo = out + (size_t)pix*6;
    float* pr = out + (size_t)LOGITS_N + (size_t)pix*6;
    float* dl = out + (size_t)DELTA_BASE + (size_t)pix*12;
    #pragma unroll
    for (int a = 0; a < 3; a++) {
        float l0 = lo[a*2]   + b_cls[a*2];
        float l1 = lo[a*2+1] + b_cls[a*2+1];
        lo[a*2] = l0; lo[a*2+1] = l1;
        float m = fmaxf(l0, l1);
        float e0 = __expf(l0 - m), e1 = __expf(l1 - m);
        float inv = 1.f / (e0 + e1);
        pr[a*2] = e0*inv; pr[a*2+1] = e1*inv;
    }
    #pragma unroll
    for (int o = 0; o < 12; o++) dl[o] += b_dlt[o];
}

extern "C" void kernel_launch(void* const* d_in, const int* in_sizes, int n_in,
                              void* d_out, int out_size, void* d_ws, size_t ws_size,
                              hipStream_t stream) {
    const float* in    = (const float*)d_in[0];
    const float* w_sh  = (const float*)d_in[1];
    const float* b_sh  = (const float*)d_in[2];
    const float* w_cls = (const float*)d_in[3];
    const float* b_cls = (const float*)d_in[4];
    const float* w_dlt = (const float*)d_in[5];
    const float* b_dlt = (const float*)d_in[6];
    float* out = (float*)d_out;

    const size_t in_p_elems = (size_t)BATCH*HP*HP*CIN;   // 17,305,600
    const size_t wt_elems   = (size_t)9*CO*CIN;          // 1,179,648
    const size_t part_elems = (size_t)2*NPIX*18;         // 2,359,296
    const size_t need = (in_p_elems + wt_elems)*2 + part_elems*4;  // ~46.4 MB

    if (ws_size >= need) {
        unsigned short* in_p = (unsigned short*)d_ws;
        unsigned short* wt   = in_p + in_p_elems;
        float* part = (float*)(wt + wt_elems);
        hipFuncSetAttribute((const void*)k_main8,
                            hipFuncAttributeMaxDynamicSharedMemorySize, 131072);
        int padq = (int)(((size_t)BATCH*HP*HP*64 + 255)/256);
        k_pad_convert<<<padq, 256, 0, stream>>>(in, in_p);
        k_wt_convert<<<9*CO, 256, 0, stream>>>(w_sh, wt);
        k_main8<<<512, 512, 131072, stream>>>(in_p, wt, b_sh, w_cls, w_dlt, part);
        k_finalize_ws<<<(NPIX + 255)/256, 256, 0, stream>>>(part, out, b_cls, b_dlt);
    } else {
        hipMemsetAsync(d_out, 0, (size_t)out_size * sizeof(float), stream);
        k_main_fb<<<2048, 256, 0, stream>>>(in, w_sh, b_sh, w_cls, w_dlt, out);
        k_finalize<<<(NPIX + 255)/256, 256, 0, stream>>>(out, b_cls, b_dlt);
    }
}

// Round 7
// 198.026 us; speedup vs baseline: 2.4281x; 1.0100x over previous
//
#include <hip/hip_runtime.h>
#include <stdint.h>

#define BATCH 4
#define HH 128
#define WW 128
#define CIN 256
#define CO 512
#define HP 130
#define NPIX (BATCH*HH*WW)          // 65536
#define LOGITS_N (NPIX*6)           // 393216
#define DELTA_BASE (2*LOGITS_N)     // 786432

typedef short bf16x8 __attribute__((ext_vector_type(8)));
typedef unsigned short u16x8 __attribute__((ext_vector_type(8)));
typedef float f32x4 __attribute__((ext_vector_type(4)));
typedef unsigned int u32;

__device__ __forceinline__ unsigned short f2bf(float f) {
    union { float f; unsigned int u; } v; v.f = f;
    return (unsigned short)((v.u + 0x7FFFu + ((v.u >> 16) & 1u)) >> 16);
}

__device__ __forceinline__ void gload16(const unsigned short* g, char* l) {
    __builtin_amdgcn_global_load_lds(
        (const __attribute__((address_space(1))) u32*)g,
        (__attribute__((address_space(3))) u32*)l, 16, 0, 0);
}

// ---- pass 1a: fp32 input -> bf16 with 1-pixel zero halo: [B][130][130][256]
__global__ __launch_bounds__(256) void k_pad_convert(const float* __restrict__ in,
                                                     unsigned short* __restrict__ out) {
    size_t q = (size_t)blockIdx.x*256 + threadIdx.x;     // quad index (4 channels)
    if (q >= (size_t)BATCH*HP*HP*64) return;
    int c4 = ((int)q & 63) * 4;
    int pix = (int)(q >> 6);
    int xx = pix % HP; int t = pix / HP; int yy = t % HP; int b = t / HP;
    ushort4 r = {0, 0, 0, 0};
    if (yy >= 1 && yy <= HH && xx >= 1 && xx <= WW) {
        const float4 v = *(const float4*)(in + (((size_t)(b*HH) + (yy-1))*WW + (xx-1))*CIN + c4);
        r.x = f2bf(v.x); r.y = f2bf(v.y); r.z = f2bf(v.z); r.w = f2bf(v.w);
    }
    *(ushort4*)(out + (size_t)pix*CIN + c4) = r;
}

// ---- pass 1b: w_shared [9][256][512] fp32 -> wT [9][512][256] bf16
__global__ __launch_bounds__(256) void k_wt_convert(const float* __restrict__ w,
                                                    unsigned short* __restrict__ wt) {
    int n = blockIdx.x % CO; int tap = blockIdx.x / CO;
    int c = threadIdx.x;
    wt[((size_t)tap*CO + n)*CIN + c] = f2bf(w[((size_t)tap*CIN + c)*CO + n]);
}

// ============ main: 256x256 tile, ONE barrier per K-step, counted vmcnt ============
// M=65536 pixels, N=512 (2 tiles), K=2304 (9 taps x 4 kq, BK=64). 512 thr, 8 waves (2Mx4N).
// LDS: 2 bufs x [A 256x64 | B 256x64] bf16 = 128 KiB dynamic.
// Step s: ds_reads from buf[cur], stages (for s+1) into buf[cur^1] -> no intra-step hazard.
__global__ __launch_bounds__(512, 2) void k_main8(
    const unsigned short* __restrict__ in_p,   // bf16 padded input
    const unsigned short* __restrict__ wt,     // bf16 wT [9][512][256]
    const float* __restrict__ b_sh,
    const float* __restrict__ w_cls,
    const float* __restrict__ w_dlt,
    float* __restrict__ part)                  // [2][NPIX][18]
{
    extern __shared__ char LDS[];

    const int tid  = threadIdx.x;
    const int lane = tid & 63, wave = tid >> 6;
    const int l15  = lane & 15, l4 = lane >> 4;
    const int wm   = wave >> 2, wn = wave & 3;

    // XCD-contiguous bijective swizzle (512 % 8 == 0)
    const int bid   = ((blockIdx.x & 7) << 6) + (blockIdx.x >> 3);
    const int ntile = bid & 1, mtile = bid >> 1;
    const int n0 = ntile << 8;
    const int b  = mtile >> 6;
    const int y0 = (mtile & 63) * 2;           // tile covers image rows y0, y0+1

    // per-thread staging offset: chunk tid -> row tid>>3, sub tid&7 (inverse XOR on source)
    const int rl0 = tid >> 3, pc0 = tid & 7;
    const int kc0 = pc0 ^ (rl0 & 7);
    const int off = rl0*256 + kc0*8;           // elements
    const int t16 = tid*16;                    // linear LDS dest byte offset

    // MFMA fragment LDS byte offsets (swizzled reads)
    int base_a[2], base_b[2];
    #pragma unroll
    for (int kk = 0; kk < 2; kk++) {
        int swz = ((kk*32 + l4*8)*2) ^ ((l15 & 7) << 4);
        base_a[kk] = (wm*128 + l15)*128 + swz;
        base_b[kk] = 32768 + (wn*64 + l15)*128 + swz;
    }

    f32x4 acc[8][4];
    const f32x4 zz = {0.f, 0.f, 0.f, 0.f};
    #pragma unroll
    for (int mi = 0; mi < 8; mi++)
        #pragma unroll
        for (int ni = 0; ni < 4; ni++) acc[mi][ni] = zz;

    // ---- prologue: stage tile 0 into buf0 (HT order: B-lo, B-hi, A-ht2, A-ht3)
    {
        const unsigned short* gB0 = wt + (size_t)n0*256;
        const unsigned short* gA0 = in_p + ((size_t)(b*HP + y0))*HP*256;
        char* Ad0 = LDS; char* Bd0 = LDS + 32768;
        gload16(gB0 + off,          Bd0 + t16);           // HT0: B cols 0-63
        gload16(gB0 + 16384 + off,  Bd0 + 8192 + t16);    //      B cols 64-127
        gload16(gB0 + 32768 + off,  Bd0 + 16384 + t16);   // HT1: B cols 128-191
        gload16(gB0 + 49152 + off,  Bd0 + 24576 + t16);   //      B cols 192-255
        gload16(gA0 + off,          Ad0 + t16);           // HT2: A rows 0-63
        gload16(gA0 + 33280 + off,  Ad0 + 16384 + t16);   //      A rows 128-191
        gload16(gA0 + 16384 + off,  Ad0 + 8192 + t16);    // HT3: A rows 64-127
        gload16(gA0 + 49664 + off,  Ad0 + 24576 + t16);   //      A rows 192-255
    }
    asm volatile("s_waitcnt vmcnt(2)" ::: "memory");      // HT0-2 landed; HT3 may fly
    __builtin_amdgcn_sched_barrier(0);
    __builtin_amdgcn_s_barrier();
    __builtin_amdgcn_sched_barrier(0);

#define MFMA_Q(Q)                                                            \
    __builtin_amdgcn_s_setprio(1);                                           \
    _Pragma("unroll")                                                        \
    for (int kk = 0; kk < 2; kk++)                                           \
        _Pragma("unroll")                                                    \
        for (int mm = 0; mm < 2; mm++)                                       \
            _Pragma("unroll")                                                \
            for (int ni = 0; ni < 4; ni++)                                   \
                acc[2*(Q)+mm][ni] = __builtin_amdgcn_mfma_f32_16x16x32_bf16( \
                    aq[mm][kk], breg[ni][kk], acc[2*(Q)+mm][ni], 0, 0, 0);   \
    __builtin_amdgcn_s_setprio(0);

#define LOAD_AQ(Q)                                                           \
    _Pragma("unroll")                                                        \
    for (int kk = 0; kk < 2; kk++) {                                         \
        aq[0][kk] = *(const bf16x8*)(bufc + base_a[kk] + (2*(Q))*2048);      \
        aq[1][kk] = *(const bf16x8*)(bufc + base_a[kk] + (2*(Q)+1)*2048);    \
    }

    for (int s = 0; s < 36; ++s) {
        const int s1 = s + 1;
        const int tap1 = s1 >> 2, kq1 = s1 & 3;
        const int dy1 = (tap1*11) >> 5, dx1 = tap1 - dy1*3;
        const unsigned short* gA = in_p + ((size_t)((b*HP + y0 + dy1)*HP + dx1))*256 + kq1*64;
        const unsigned short* gB = wt + ((size_t)(tap1*512 + n0))*256 + kq1*64;
        const int cur = s & 1;
        const char* bufc = LDS + (cur << 16);
        char* Ad = LDS + ((cur ^ 1) << 16);
        char* Bd = Ad + 32768;
        const bool more = (s < 35);

        // ---- issue ALL stages for step s+1 up front (8 gload_lds, ~1 step of slack)
        if (more) {
            gload16(gB + off,          Bd + t16);
            gload16(gB + 16384 + off,  Bd + 8192 + t16);
            gload16(gB + 32768 + off,  Bd + 16384 + t16);
            gload16(gB + 49152 + off,  Bd + 24576 + t16);
            gload16(gA + off,          Ad + t16);
            gload16(gA + 33280 + off,  Ad + 16384 + t16);
            gload16(gA + 16384 + off,  Ad + 8192 + t16);
            gload16(gA + 49664 + off,  Ad + 24576 + t16);
        }

        // ---- B once per step; A quad-by-quad; compiler pipelines lgkmcnt finely
        bf16x8 breg[4][2];
        #pragma unroll
        for (int kk = 0; kk < 2; kk++) {
            breg[0][kk] = *(const bf16x8*)(bufc + base_b[kk]);
            breg[1][kk] = *(const bf16x8*)(bufc + base_b[kk] + 2048);
            breg[2][kk] = *(const bf16x8*)(bufc + base_b[kk] + 4096);
            breg[3][kk] = *(const bf16x8*)(bufc + base_b[kk] + 6144);
        }
        bf16x8 aq[2][2];
        LOAD_AQ(0)
        MFMA_Q(0)
        LOAD_AQ(1)
        MFMA_Q(1)
        // HT3(s) must be landed before quad2/3 reads (rows 64-127,192-255).
        // Outstanding newer loads: the 8 stages for s+1 (none at s=35).
        if (more) { asm volatile("s_waitcnt vmcnt(8)" ::: "memory"); }
        else      { asm volatile("s_waitcnt vmcnt(0)" ::: "memory"); }
        __builtin_amdgcn_sched_barrier(0);
        LOAD_AQ(2)
        MFMA_Q(2)
        LOAD_AQ(3)
        MFMA_Q(3)

        // ---- boundary: HT0-2(s+1) landed (HT3 may fly); all reads of bufc retired
        if (more) { asm volatile("s_waitcnt vmcnt(2)" ::: "memory"); }
        __builtin_amdgcn_sched_barrier(0);
        __builtin_amdgcn_s_barrier();
        __builtin_amdgcn_sched_barrier(0);
    }
#undef MFMA_Q
#undef LOAD_AQ

    // ---- epilogue: bias+ReLU + 1x1-head partial reduction over this block's 256 channels
    float* shf = (float*)LDS;                  // [64 cols][260]
    float* sW  = (float*)(LDS + 66560);        // [256][20]
    for (int j = tid; j < 256*18; j += 512) {
        int c = j / 18, o = j - c*18;
        sW[c*20 + o] = (o < 6) ? w_cls[(size_t)(n0 + c)*6 + o]
                               : w_dlt[(size_t)(n0 + c)*12 + (o - 6)];
    }
    float bsh[4];
    #pragma unroll
    for (int ni = 0; ni < 4; ni++) bsh[ni] = b_sh[n0 + wn*64 + ni*16 + l15];

    float a18[18];
    #pragma unroll
    for (int o = 0; o < 18; o++) a18[o] = 0.f;
    const int rr = tid & 255, chalf = tid >> 8;
    __syncthreads();

    for (int p = 0; p < 4; ++p) {
        if (wn == p) {
            #pragma unroll
            for (int mi = 0; mi < 8; mi++)
                #pragma unroll
                for (int ni = 0; ni < 4; ni++) {
                    int colL = ni*16 + l15;
                    int row0 = wm*128 + mi*16 + l4*4;
                    f32x4 v = acc[mi][ni];
                    f32x4 sv;
                    #pragma unroll
                    for (int r = 0; r < 4; r++) sv[r] = fmaxf(v[r] + bsh[ni], 0.f);
                    *(f32x4*)(shf + colL*260 + row0) = sv;
                }
        }
        __syncthreads();
        #pragma unroll 4
        for (int i = 0; i < 32; i++) {
            int c = chalf*32 + i;
            float v = shf[c*260 + rr];
            const float* wrow = sW + (p*64 + c)*20;
            #pragma unroll
            for (int o = 0; o < 18; o++) a18[o] += v * wrow[o];
        }
        __syncthreads();
    }

    if (chalf == 1) {
        #pragma unroll
        for (int o = 0; o < 18; o++) shf[rr*18 + o] = a18[o];
    }
    __syncthreads();
    if (chalf == 0) {
        float* dst = part + ((size_t)ntile*NPIX + (size_t)mtile*256 + rr)*18;
        #pragma unroll
        for (int o = 0; o < 18; o++) dst[o] = a18[o] + shf[rr*18 + o];
    }
}

// ---- finalize (ws path): sum 2 partials, biases, softmax -> all outputs
__global__ __launch_bounds__(256) void k_finalize_ws(const float* __restrict__ part,
                                                     float* __restrict__ out,
                                                     const float* __restrict__ b_cls,
                                                     const float* __restrict__ b_dlt) {
    int pix = blockIdx.x*256 + threadIdx.x;
    if (pix >= NPIX) return;
    float s[18];
    #pragma unroll
    for (int o = 0; o < 18; o++)
        s[o] = part[(size_t)pix*18 + o] + part[((size_t)NPIX + pix)*18 + o];
    float* lo = out + (size_t)pix*6;
    float* pr = out + (size_t)LOGITS_N + (size_t)pix*6;
    float* dl = out + (size_t)DELTA_BASE + (size_t)pix*12;
    #pragma unroll
    for (int a = 0; a < 3; a++) {
        float l0 = s[a*2]   + b_cls[a*2];
        float l1 = s[a*2+1] + b_cls[a*2+1];
        lo[a*2] = l0; lo[a*2+1] = l1;
        float m = fmaxf(l0, l1);
        float e0 = __expf(l0 - m), e1 = __expf(l1 - m);
        float inv = 1.f / (e0 + e1);
        pr[a*2] = e0*inv; pr[a*2+1] = e1*inv;
    }
    #pragma unroll
    for (int o = 0; o < 12; o++) dl[o] = s[6 + o] + b_dlt[o];
}

// ======== fallback path (no workspace): round-2 proven kernel, atomics ========
__global__ __launch_bounds__(256) void k_main_fb(
    const float* __restrict__ in_f, const float* __restrict__ w_f,
    const float* __restrict__ b_sh, const float* __restrict__ w_cls,
    const float* __restrict__ w_dlt, float* __restrict__ out)
{
    __shared__ float smemf[11008];
    char* smem  = (char*)smemf;
    char* smemB = smem + 16384;
    const int tid = threadIdx.x;
    const int lane = tid & 63, wave = tid >> 6;
    const int l15 = lane & 15, l4 = lane >> 4;
    const int wr = wave >> 1, wc = wave & 1;
    int bid = ((blockIdx.x & 7) << 8) + (blockIdx.x >> 3);
    const int ntile = bid & 3, mtile = bid >> 2;
    const int n0 = ntile << 7;
    const int b = mtile >> 7, y = mtile & 127;
    int aoff[4][2], boff[4][2];
    #pragma unroll
    for (int mi = 0; mi < 4; mi++) {
        int rowA = wr*64 + mi*16 + l15;
        int rowB = wc*64 + mi*16 + l15;
        #pragma unroll
        for (int kk = 0; kk < 2; kk++) {
            int kb = (kk*32 + l4*8) * 2;
            aoff[mi][kk] = rowA*128 + (kb ^ ((rowA & 7) << 4));
            boff[mi][kk] = rowB*128 + (kb ^ ((rowB & 7) << 4));
        }
    }
    f32x4 acc[4][4];
    const f32x4 zz = {0.f, 0.f, 0.f, 0.f};
    #pragma unroll
    for (int mi = 0; mi < 4; mi++)
        #pragma unroll
        for (int ni = 0; ni < 4; ni++) acc[mi][ni] = zz;
    for (int s = 0; s < 36; s++) {
        int tap = s >> 2, kq = s & 3;
        int dy = tap / 3, dx = tap - dy*3;
        const int c0 = kq * 64;
        const int yy = y + dy - 1;
        const bool yok = (yy >= 0) && (yy < HH);
        #pragma unroll
        for (int i = 0; i < 4; i++) {
            int ci = i*256 + tid;
            int row = ci >> 3, pc = ci & 7;
            int kc = pc ^ (row & 7);
            int xx = row + dx - 1;
            u16x8 a;
            if (yok && xx >= 0 && xx < WW) {
                const float* sp = in_f + (((size_t)(b*HH) + yy)*WW + xx)*CIN + c0 + kc*8;
                #pragma unroll
                for (int j = 0; j < 8; j++) a[j] = (short)f2bf(sp[j]);
            } else {
                #pragma unroll
                for (int j = 0; j < 8; j++) a[j] = 0;
            }
            *(u16x8*)(smem + ci*16) = a;
            const float* wsrc = w_f + ((size_t)(tap*CIN + c0 + kc*8))*CO + n0 + row;
            u16x8 bb;
            #pragma unroll
            for (int j = 0; j < 8; j++) bb[j] = (short)f2bf(wsrc[(size_t)j*CO]);
            *(u16x8*)(smemB + ci*16) = bb;
        }
        __syncthreads();
        #pragma unroll
        for (int kk = 0; kk < 2; kk++) {
            bf16x8 av[4], bv[4];
            #pragma unroll
            for (int mi = 0; mi < 4; mi++) av[mi] = *(const bf16x8*)(smem  + aoff[mi][kk]);
            #pragma unroll
            for (int ni = 0; ni < 4; ni++) bv[ni] = *(const bf16x8*)(smemB + boff[ni][kk]);
            #pragma unroll
            for (int mi = 0; mi < 4; mi++)
                #pragma unroll
                for (int ni = 0; ni < 4; ni++)
                    acc[mi][ni] = __builtin_amdgcn_mfma_f32_16x16x32_bf16(
                        av[mi], bv[ni], acc[mi][ni], 0, 0, 0);
        }
        __syncthreads();
    }
    float* shf = smemf;
    float* sW  = smemf + 8448;
    for (int j = tid; j < 128*18; j += 256) {
        int c = j / 18, o = j - c*18;
        sW[c*20 + o] = (o < 6) ? w_cls[(size_t)(n0 + c)*6 + o]
                               : w_dlt[(size_t)(n0 + c)*12 + (o - 6)];
    }
    float bsh[4];
    #pragma unroll
    for (int ni = 0; ni < 4; ni++) bsh[ni] = b_sh[n0 + wc*64 + ni*16 + l15];
    float a18[18];
    #pragma unroll
    for (int o = 0; o < 18; o++) a18[o] = 0.f;
    const int rr = tid & 127, chalf = tid >> 7;
    #pragma unroll
    for (int pass = 0; pass < 2; pass++) {
        if (wc == pass) {
            #pragma unroll
            for (int mi = 0; mi < 4; mi++)
                #pragma unroll
                for (int ni = 0; ni < 4; ni++) {
                    int colL = ni*16 + l15;
                    int row0 = wr*64 + mi*16 + l4*4;
                    f32x4 v = acc[mi][ni];
                    f32x4 sv;
                    #pragma unroll
                    for (int r = 0; r < 4; r++) sv[r] = fmaxf(v[r] + bsh[ni], 0.f);
                    *(f32x4*)(shf + colL*132 + row0) = sv;
                }
        }
        __syncthreads();
        #pragma unroll 4
        for (int i = 0; i < 32; i++) {
            int c = chalf*32 + i;
            float v = shf[c*132 + rr];
            const float* wrow = sW + (pass*64 + c)*20;
            #pragma unroll
            for (int o = 0; o < 18; o++) a18[o] += v * wrow[o];
        }
        __syncthreads();
    }
    const int pixel = mtile*128 + rr;
    float* lo = out + (size_t)pixel*6;
    float* dl = out + DELTA_BASE + (size_t)pixel*12;
    #pragma unroll
    for (int o = 0; o < 6; o++)  atomicAdd(lo + o, a18[o]);
    #pragma unroll
    for (int o = 0; o < 12; o++) atomicAdd(dl + o, a18[6 + o]);
}

__global__ __launch_bounds__(256) void k_finalize(float* __restrict__ out,
                                                  const float* __restrict__ b_cls,
                                                  const float* __restrict__ b_dlt) {
    int pix = blockIdx.x*256 + threadIdx.x;
    if (pix >= NPIX) return;
    float* lo = out + (size_t)pix*6;
    float* pr = out + (size_t)LOGITS_N + (size_t)pix*6;
    float* dl = out + (size_t)DELTA_BASE + (size_t)pix*12;
    #pragma unroll
    for (int a = 0; a < 3; a++) {
        float l0 = lo[a*2]   + b_cls[a*2];
        float l1 = lo[a*2+1] + b_cls[a*2+1];
        lo[a*2] = l0; lo[a*2+1] = l1;
        float m = fmaxf(l0, l1);
        float e0 = __expf(l0 - m), e1 = __expf(l1 - m);
        float inv = 1.f / (e0 + e1);
        pr[a*2] = e0*inv; pr[a*2+1] = e1*inv;
    }
    #pragma unroll
    for (int o = 0; o < 12; o++) dl[o] += b_dlt[o];
}

extern "C" void kernel_launch(void* const* d_in, const int* in_sizes, int n_in,
                              void* d_out, int out_size, void* d_ws, size_t ws_size,
                              hipStream_t stream) {
    const float* in    = (const float*)d_in[0];
    const float* w_sh  = (const float*)d_in[1];
    const float* b_sh  = (const float*)d_in[2];
    const float* w_cls = (const float*)d_in[3];
    const float* b_cls = (const float*)d_in[4];
    const float* w_dlt = (const float*)d_in[5];
    const float* b_dlt = (const float*)d_in[6];
    float* out = (float*)d_out;

    const size_t in_p_elems = (size_t)BATCH*HP*HP*CIN;   // 17,305,600
    const size_t wt_elems   = (size_t)9*CO*CIN;          // 1,179,648
    const size_t part_elems = (size_t)2*NPIX*18;         // 2,359,296
    const size_t need = (in_p_elems + wt_elems)*2 + part_elems*4;  // ~46.4 MB

    if (ws_size >= need) {
        unsigned short* in_p = (unsigned short*)d_ws;
        unsigned short* wt   = in_p + in_p_elems;
        float* part = (float*)(wt + wt_elems);
        hipFuncSetAttribute((const void*)k_main8,
                            hipFuncAttributeMaxDynamicSharedMemorySize, 131072);
        int padq = (int)(((size_t)BATCH*HP*HP*64 + 255)/256);
        k_pad_convert<<<padq, 256, 0, stream>>>(in, in_p);
        k_wt_convert<<<9*CO, 256, 0, stream>>>(w_sh, wt);
        k_main8<<<512, 512, 131072, stream>>>(in_p, wt, b_sh, w_cls, w_dlt, part);
        k_finalize_ws<<<(NPIX + 255)/256, 256, 0, stream>>>(part, out, b_cls, b_dlt);
    } else {
        hipMemsetAsync(d_out, 0, (size_t)out_size * sizeof(float), stream);
        k_main_fb<<<2048, 256, 0, stream>>>(in, w_sh, b_sh, w_cls, w_dlt, out);
        k_finalize<<<(NPIX + 255)/256, 256, 0, stream>>>(out, b_cls, b_dlt);
    }
}

// Round 8
// 193.131 us; speedup vs baseline: 2.4897x; 1.0253x over previous
//
#include <hip/hip_runtime.h>
#include <stdint.h>

#define BATCH 4
#define HH 128
#define WW 128
#define CIN 256
#define CO 512
#define HP 130
#define NPIX (BATCH*HH*WW)          // 65536
#define LOGITS_N (NPIX*6)           // 393216
#define DELTA_BASE (2*LOGITS_N)     // 786432

typedef short bf16x8 __attribute__((ext_vector_type(8)));
typedef unsigned short u16x8 __attribute__((ext_vector_type(8)));
typedef float f32x4 __attribute__((ext_vector_type(4)));
typedef unsigned int u32;

__device__ __forceinline__ unsigned short f2bf(float f) {
    union { float f; unsigned int u; } v; v.f = f;
    return (unsigned short)((v.u + 0x7FFFu + ((v.u >> 16) & 1u)) >> 16);
}

__device__ __forceinline__ void gload16(const unsigned short* g, char* l) {
    __builtin_amdgcn_global_load_lds(
        (const __attribute__((address_space(1))) u32*)g,
        (__attribute__((address_space(3))) u32*)l, 16, 0, 0);
}

// ---- pass 1a: fp32 input -> bf16 with 1-pixel zero halo: [B][130][130][256]
__global__ __launch_bounds__(256) void k_pad_convert(const float* __restrict__ in,
                                                     unsigned short* __restrict__ out) {
    size_t q = (size_t)blockIdx.x*256 + threadIdx.x;     // quad index (4 channels)
    if (q >= (size_t)BATCH*HP*HP*64) return;
    int c4 = ((int)q & 63) * 4;
    int pix = (int)(q >> 6);
    int xx = pix % HP; int t = pix / HP; int yy = t % HP; int b = t / HP;
    ushort4 r = {0, 0, 0, 0};
    if (yy >= 1 && yy <= HH && xx >= 1 && xx <= WW) {
        const float4 v = *(const float4*)(in + (((size_t)(b*HH) + (yy-1))*WW + (xx-1))*CIN + c4);
        r.x = f2bf(v.x); r.y = f2bf(v.y); r.z = f2bf(v.z); r.w = f2bf(v.w);
    }
    *(ushort4*)(out + (size_t)pix*CIN + c4) = r;
}

// ---- pass 1b: w_shared [9][256][512] fp32 -> wT [9][512][256] bf16
__global__ __launch_bounds__(256) void k_wt_convert(const float* __restrict__ w,
                                                    unsigned short* __restrict__ wt) {
    int n = blockIdx.x % CO; int tap = blockIdx.x / CO;
    int c = threadIdx.x;
    wt[((size_t)tap*CO + n)*CIN + c] = f2bf(w[((size_t)tap*CIN + c)*CO + n]);
}

// ============ main: 256x256 tile, 1 barrier/step, counted vmcnt, quad read-ahead ============
// M=65536 pixels, N=512 (2 tiles), K=2304 (9 taps x 4 kq, BK=64). 512 thr, 8 waves (2Mx4N).
// LDS: 2 bufs x [A 256x64 | B 256x64] bf16 = 128 KiB dynamic.
// Step s: ds_reads from buf[cur], stages (for s+1) into buf[cur^1]; A-quad q+1 reads are
// issued BEFORE MFMA quad q so LDS latency hides under the MFMA cluster.
__global__ __launch_bounds__(512, 2) void k_main8(
    const unsigned short* __restrict__ in_p,   // bf16 padded input
    const unsigned short* __restrict__ wt,     // bf16 wT [9][512][256]
    const float* __restrict__ b_sh,
    const float* __restrict__ w_cls,
    const float* __restrict__ w_dlt,
    float* __restrict__ part)                  // [2][NPIX][18]
{
    extern __shared__ char LDS[];

    const int tid  = threadIdx.x;
    const int lane = tid & 63, wave = tid >> 6;
    const int l15  = lane & 15, l4 = lane >> 4;
    const int wm   = wave >> 2, wn = wave & 3;

    // XCD-contiguous bijective swizzle (512 % 8 == 0)
    const int bid   = ((blockIdx.x & 7) << 6) + (blockIdx.x >> 3);
    const int ntile = bid & 1, mtile = bid >> 1;
    const int n0 = ntile << 8;
    const int b  = mtile >> 6;
    const int y0 = (mtile & 63) * 2;           // tile covers image rows y0, y0+1

    // per-thread staging offset: chunk tid -> row tid>>3, sub tid&7 (inverse XOR on source)
    const int rl0 = tid >> 3, pc0 = tid & 7;
    const int kc0 = pc0 ^ (rl0 & 7);
    const int off = rl0*256 + kc0*8;           // elements
    const int t16 = tid*16;                    // linear LDS dest byte offset

    // MFMA fragment LDS byte offsets (swizzled reads)
    int base_a[2], base_b[2];
    #pragma unroll
    for (int kk = 0; kk < 2; kk++) {
        int swz = ((kk*32 + l4*8)*2) ^ ((l15 & 7) << 4);
        base_a[kk] = (wm*128 + l15)*128 + swz;
        base_b[kk] = 32768 + (wn*64 + l15)*128 + swz;
    }

    f32x4 acc[8][4];
    const f32x4 zz = {0.f, 0.f, 0.f, 0.f};
    #pragma unroll
    for (int mi = 0; mi < 8; mi++)
        #pragma unroll
        for (int ni = 0; ni < 4; ni++) acc[mi][ni] = zz;

    // ---- prologue: stage tile 0 into buf0 (order: B-HT0, B-HT1, A-ht2, A-ht3)
    {
        const unsigned short* gB0 = wt + (size_t)n0*256;
        const unsigned short* gA0 = in_p + ((size_t)(b*HP + y0))*HP*256;
        char* Ad0 = LDS; char* Bd0 = LDS + 32768;
        gload16(gB0 + off,          Bd0 + t16);           // HT0: B cols 0-63
        gload16(gB0 + 16384 + off,  Bd0 + 8192 + t16);    //      B cols 64-127
        gload16(gB0 + 32768 + off,  Bd0 + 16384 + t16);   // HT1: B cols 128-191
        gload16(gB0 + 49152 + off,  Bd0 + 24576 + t16);   //      B cols 192-255
        gload16(gA0 + off,          Ad0 + t16);           // HT2: A rows 0-63
        gload16(gA0 + 33280 + off,  Ad0 + 16384 + t16);   //      A rows 128-191
        gload16(gA0 + 16384 + off,  Ad0 + 8192 + t16);    // HT3: A rows 64-127
        gload16(gA0 + 49664 + off,  Ad0 + 24576 + t16);   //      A rows 192-255
    }
    asm volatile("s_waitcnt vmcnt(2)" ::: "memory");      // HT0-2 landed; HT3 may fly
    __builtin_amdgcn_sched_barrier(0);
    __builtin_amdgcn_s_barrier();
    __builtin_amdgcn_sched_barrier(0);

#define MFMA_Q(Q, AQ)                                                        \
    __builtin_amdgcn_s_setprio(1);                                           \
    _Pragma("unroll")                                                        \
    for (int kk = 0; kk < 2; kk++)                                           \
        _Pragma("unroll")                                                    \
        for (int mm = 0; mm < 2; mm++)                                       \
            _Pragma("unroll")                                                \
            for (int ni = 0; ni < 4; ni++)                                   \
                acc[2*(Q)+mm][ni] = __builtin_amdgcn_mfma_f32_16x16x32_bf16( \
                    AQ[mm][kk], breg[ni][kk], acc[2*(Q)+mm][ni], 0, 0, 0);   \
    __builtin_amdgcn_s_setprio(0);

#define LOAD_Q(AQ, Q)                                                        \
    _Pragma("unroll")                                                        \
    for (int kk = 0; kk < 2; kk++) {                                         \
        AQ[0][kk] = *(const bf16x8*)(bufc + base_a[kk] + (2*(Q))*2048);      \
        AQ[1][kk] = *(const bf16x8*)(bufc + base_a[kk] + (2*(Q)+1)*2048);    \
    }

    for (int s = 0; s < 36; ++s) {
        const int s1 = s + 1;
        const int tap1 = s1 >> 2, kq1 = s1 & 3;
        const int dy1 = (tap1*11) >> 5, dx1 = tap1 - dy1*3;
        const unsigned short* gA = in_p + ((size_t)((b*HP + y0 + dy1)*HP + dx1))*256 + kq1*64;
        const unsigned short* gB = wt + ((size_t)(tap1*512 + n0))*256 + kq1*64;
        const int cur = s & 1;
        const char* bufc = LDS + (cur << 16);
        char* Ad = LDS + ((cur ^ 1) << 16);
        char* Bd = Ad + 32768;
        const bool more = (s < 35);

        bf16x8 a0[2][2], a1[2][2], a2[2][2], a3[2][2];
        bf16x8 breg[4][2];

        // a0 + B reads first (first MFMA's deps are the oldest lgkm entries)
        LOAD_Q(a0, 0)
        #pragma unroll
        for (int kk = 0; kk < 2; kk++) {
            breg[0][kk] = *(const bf16x8*)(bufc + base_b[kk]);
            breg[1][kk] = *(const bf16x8*)(bufc + base_b[kk] + 2048);
            breg[2][kk] = *(const bf16x8*)(bufc + base_b[kk] + 4096);
            breg[3][kk] = *(const bf16x8*)(bufc + base_b[kk] + 6144);
        }
        // stage B(s+1): HT0, HT1
        if (more) {
            gload16(gB + off,          Bd + t16);
            gload16(gB + 16384 + off,  Bd + 8192 + t16);
            gload16(gB + 32768 + off,  Bd + 16384 + t16);
            gload16(gB + 49152 + off,  Bd + 24576 + t16);
        }
        LOAD_Q(a1, 1)
        MFMA_Q(0, a0)

        // HT3(s) must be landed before quad2/3 reads (rows 64-127 / 192-255).
        // Outstanding newer per wave: the 4 B-stages just issued (0 at s=35).
        if (more) { asm volatile("s_waitcnt vmcnt(4)" ::: "memory"); }
        else      { asm volatile("s_waitcnt vmcnt(0)" ::: "memory"); }
        __builtin_amdgcn_sched_barrier(0);

        LOAD_Q(a2, 2)
        // stage A(s+1): HT2, HT3
        if (more) {
            gload16(gA + off,          Ad + t16);
            gload16(gA + 33280 + off,  Ad + 16384 + t16);
            gload16(gA + 16384 + off,  Ad + 8192 + t16);
            gload16(gA + 49664 + off,  Ad + 24576 + t16);
        }
        MFMA_Q(1, a1)
        LOAD_Q(a3, 3)
        MFMA_Q(2, a2)
        MFMA_Q(3, a3)

        // boundary: HT0-2(s+1) landed (A-ht3(s+1) may fly); reads of bufc all retired
        if (more) { asm volatile("s_waitcnt vmcnt(2)" ::: "memory"); }
        __builtin_amdgcn_sched_barrier(0);
        __builtin_amdgcn_s_barrier();
        __builtin_amdgcn_sched_barrier(0);
    }
#undef MFMA_Q
#undef LOAD_Q

    // ---- epilogue: bias+ReLU + 1x1-head partial reduction over this block's 256 channels
    float* shf = (float*)LDS;                  // [64 cols][260]
    float* sW  = (float*)(LDS + 66560);        // [256][20]
    for (int j = tid; j < 256*18; j += 512) {
        int c = j / 18, o = j - c*18;
        sW[c*20 + o] = (o < 6) ? w_cls[(size_t)(n0 + c)*6 + o]
                               : w_dlt[(size_t)(n0 + c)*12 + (o - 6)];
    }
    float bsh[4];
    #pragma unroll
    for (int ni = 0; ni < 4; ni++) bsh[ni] = b_sh[n0 + wn*64 + ni*16 + l15];

    float a18[18];
    #pragma unroll
    for (int o = 0; o < 18; o++) a18[o] = 0.f;
    const int rr = tid & 255, chalf = tid >> 8;
    __syncthreads();

    for (int p = 0; p < 4; ++p) {
        if (wn == p) {
            #pragma unroll
            for (int mi = 0; mi < 8; mi++)
                #pragma unroll
                for (int ni = 0; ni < 4; ni++) {
                    int colL = ni*16 + l15;
                    int row0 = wm*128 + mi*16 + l4*4;
                    f32x4 v = acc[mi][ni];
                    f32x4 sv;
                    #pragma unroll
                    for (int r = 0; r < 4; r++) sv[r] = fmaxf(v[r] + bsh[ni], 0.f);
                    *(f32x4*)(shf + colL*260 + row0) = sv;
                }
        }
        __syncthreads();
        #pragma unroll 4
        for (int i = 0; i < 32; i++) {
            int c = chalf*32 + i;
            float v = shf[c*260 + rr];
            const float* wrow = sW + (p*64 + c)*20;
            #pragma unroll
            for (int o = 0; o < 18; o++) a18[o] += v * wrow[o];
        }
        __syncthreads();
    }

    if (chalf == 1) {
        #pragma unroll
        for (int o = 0; o < 18; o++) shf[rr*18 + o] = a18[o];
    }
    __syncthreads();
    if (chalf == 0) {
        float* dst = part + ((size_t)ntile*NPIX + (size_t)mtile*256 + rr)*18;
        #pragma unroll
        for (int o = 0; o < 18; o++) dst[o] = a18[o] + shf[rr*18 + o];
    }
}

// ---- finalize (ws path): sum 2 partials, biases, softmax -> all outputs
__global__ __launch_bounds__(256) void k_finalize_ws(const float* __restrict__ part,
                                                     float* __restrict__ out,
                                                     const float* __restrict__ b_cls,
                                                     const float* __restrict__ b_dlt) {
    int pix = blockIdx.x*256 + threadIdx.x;
    if (pix >= NPIX) return;
    float s[18];
    #pragma unroll
    for (int o = 0; o < 18; o++)
        s[o] = part[(size_t)pix*18 + o] + part[((size_t)NPIX + pix)*18 + o];
    float* lo = out + (size_t)pix*6;
    float* pr = out + (size_t)LOGITS_N + (size_t)pix*6;
    float* dl = out + (size_t)DELTA_BASE + (size_t)pix*12;
    #pragma unroll
    for (int a = 0; a < 3; a++) {
        float l0 = s[a*2]   + b_cls[a*2];
        float l1 = s[a*2+1] + b_cls[a*2+1];
        lo[a*2] = l0; lo[a*2+1] = l1;
        float m = fmaxf(l0, l1);
        float e0 = __expf(l0 - m), e1 = __expf(l1 - m);
        float inv = 1.f / (e0 + e1);
        pr[a*2] = e0*inv; pr[a*2+1] = e1*inv;
    }
    #pragma unroll
    for (int o = 0; o < 12; o++) dl[o] = s[6 + o] + b_dlt[o];
}

// ======== fallback path (no workspace): round-2 proven kernel, atomics ========
__global__ __launch_bounds__(256) void k_main_fb(
    const float* __restrict__ in_f, const float* __restrict__ w_f,
    const float* __restrict__ b_sh, const float* __restrict__ w_cls,
    const float* __restrict__ w_dlt, float* __restrict__ out)
{
    __shared__ float smemf[11008];
    char* smem  = (char*)smemf;
    char* smemB = smem + 16384;
    const int tid = threadIdx.x;
    const int lane = tid & 63, wave = tid >> 6;
    const int l15 = lane & 15, l4 = lane >> 4;
    const int wr = wave >> 1, wc = wave & 1;
    int bid = ((blockIdx.x & 7) << 8) + (blockIdx.x >> 3);
    const int ntile = bid & 3, mtile = bid >> 2;
    const int n0 = ntile << 7;
    const int b = mtile >> 7, y = mtile & 127;
    int aoff[4][2], boff[4][2];
    #pragma unroll
    for (int mi = 0; mi < 4; mi++) {
        int rowA = wr*64 + mi*16 + l15;
        int rowB = wc*64 + mi*16 + l15;
        #pragma unroll
        for (int kk = 0; kk < 2; kk++) {
            int kb = (kk*32 + l4*8) * 2;
            aoff[mi][kk] = rowA*128 + (kb ^ ((rowA & 7) << 4));
            boff[mi][kk] = rowB*128 + (kb ^ ((rowB & 7) << 4));
        }
    }
    f32x4 acc[4][4];
    const f32x4 zz = {0.f, 0.f, 0.f, 0.f};
    #pragma unroll
    for (int mi = 0; mi < 4; mi++)
        #pragma unroll
        for (int ni = 0; ni < 4; ni++) acc[mi][ni] = zz;
    for (int s = 0; s < 36; s++) {
        int tap = s >> 2, kq = s & 3;
        int dy = tap / 3, dx = tap - dy*3;
        const int c0 = kq * 64;
        const int yy = y + dy - 1;
        const bool yok = (yy >= 0) && (yy < HH);
        #pragma unroll
        for (int i = 0; i < 4; i++) {
            int ci = i*256 + tid;
            int row = ci >> 3, pc = ci & 7;
            int kc = pc ^ (row & 7);
            int xx = row + dx - 1;
            u16x8 a;
            if (yok && xx >= 0 && xx < WW) {
                const float* sp = in_f + (((size_t)(b*HH) + yy)*WW + xx)*CIN + c0 + kc*8;
                #pragma unroll
                for (int j = 0; j < 8; j++) a[j] = (short)f2bf(sp[j]);
            } else {
                #pragma unroll
                for (int j = 0; j < 8; j++) a[j] = 0;
            }
            *(u16x8*)(smem + ci*16) = a;
            const float* wsrc = w_f + ((size_t)(tap*CIN + c0 + kc*8))*CO + n0 + row;
            u16x8 bb;
            #pragma unroll
            for (int j = 0; j < 8; j++) bb[j] = (short)f2bf(wsrc[(size_t)j*CO]);
            *(u16x8*)(smemB + ci*16) = bb;
        }
        __syncthreads();
        #pragma unroll
        for (int kk = 0; kk < 2; kk++) {
            bf16x8 av[4], bv[4];
            #pragma unroll
            for (int mi = 0; mi < 4; mi++) av[mi] = *(const bf16x8*)(smem  + aoff[mi][kk]);
            #pragma unroll
            for (int ni = 0; ni < 4; ni++) bv[ni] = *(const bf16x8*)(smemB + boff[ni][kk]);
            #pragma unroll
            for (int mi = 0; mi < 4; mi++)
                #pragma unroll
                for (int ni = 0; ni < 4; ni++)
                    acc[mi][ni] = __builtin_amdgcn_mfma_f32_16x16x32_bf16(
                        av[mi], bv[ni], acc[mi][ni], 0, 0, 0);
        }
        __syncthreads();
    }
    float* shf = smemf;
    float* sW  = smemf + 8448;
    for (int j = tid; j < 128*18; j += 256) {
        int c = j / 18, o = j - c*18;
        sW[c*20 + o] = (o < 6) ? w_cls[(size_t)(n0 + c)*6 + o]
                               : w_dlt[(size_t)(n0 + c)*12 + (o - 6)];
    }
    float bsh[4];
    #pragma unroll
    for (int ni = 0; ni < 4; ni++) bsh[ni] = b_sh[n0 + wc*64 + ni*16 + l15];
    float a18[18];
    #pragma unroll
    for (int o = 0; o < 18; o++) a18[o] = 0.f;
    const int rr = tid & 127, chalf = tid >> 7;
    #pragma unroll
    for (int pass = 0; pass < 2; pass++) {
        if (wc == pass) {
            #pragma unroll
            for (int mi = 0; mi < 4; mi++)
                #pragma unroll
                for (int ni = 0; ni < 4; ni++) {
                    int colL = ni*16 + l15;
                    int row0 = wr*64 + mi*16 + l4*4;
                    f32x4 v = acc[mi][ni];
                    f32x4 sv;
                    #pragma unroll
                    for (int r = 0; r < 4; r++) sv[r] = fmaxf(v[r] + bsh[ni], 0.f);
                    *(f32x4*)(shf + colL*132 + row0) = sv;
                }
        }
        __syncthreads();
        #pragma unroll 4
        for (int i = 0; i < 32; i++) {
            int c = chalf*32 + i;
            float v = shf[c*132 + rr];
            const float* wrow = sW + (pass*64 + c)*20;
            #pragma unroll
            for (int o = 0; o < 18; o++) a18[o] += v * wrow[o];
        }
        __syncthreads();
    }
    const int pixel = mtile*128 + rr;
    float* lo = out + (size_t)pixel*6;
    float* dl = out + DELTA_BASE + (size_t)pixel*12;
    #pragma unroll
    for (int o = 0; o < 6; o++)  atomicAdd(lo + o, a18[o]);
    #pragma unroll
    for (int o = 0; o < 12; o++) atomicAdd(dl + o, a18[6 + o]);
}

__global__ __launch_bounds__(256) void k_finalize(float* __restrict__ out,
                                                  const float* __restrict__ b_cls,
                                                  const float* __restrict__ b_dlt) {
    int pix = blockIdx.x*256 + threadIdx.x;
    if (pix >= NPIX) return;
    float* lo = out + (size_t)pix*6;
    float* pr = out + (size_t)LOGITS_N + (size_t)pix*6;
    float* dl = out + (size_t)DELTA_BASE + (size_t)pix*12;
    #pragma unroll
    for (int a = 0; a < 3; a++) {
        float l0 = lo[a*2]   + b_cls[a*2];
        float l1 = lo[a*2+1] + b_cls[a*2+1];
        lo[a*2] = l0; lo[a*2+1] = l1;
        float m = fmaxf(l0, l1);
        float e0 = __expf(l0 - m), e1 = __expf(l1 - m);
        float inv = 1.f / (e0 + e1);
        pr[a*2] = e0*inv; pr[a*2+1] = e1*inv;
    }
    #pragma unroll
    for (int o = 0; o < 12; o++) dl[o] += b_dlt[o];
}

extern "C" void kernel_launch(void* const* d_in, const int* in_sizes, int n_in,
                              void* d_out, int out_size, void* d_ws, size_t ws_size,
                              hipStream_t stream) {
    const float* in    = (const float*)d_in[0];
    const float* w_sh  = (const float*)d_in[1];
    const float* b_sh  = (const float*)d_in[2];
    const float* w_cls = (const float*)d_in[3];
    const float* b_cls = (const float*)d_in[4];
    const float* w_dlt = (const float*)d_in[5];
    const float* b_dlt = (const float*)d_in[6];
    float* out = (float*)d_out;

    const size_t in_p_elems = (size_t)BATCH*HP*HP*CIN;   // 17,305,600
    const size_t wt_elems   = (size_t)9*CO*CIN;          // 1,179,648
    const size_t part_elems = (size_t)2*NPIX*18;         // 2,359,296
    const size_t need = (in_p_elems + wt_elems)*2 + part_elems*4;  // ~46.4 MB

    if (ws_size >= need) {
        unsigned short* in_p = (unsigned short*)d_ws;
        unsigned short* wt   = in_p + in_p_elems;
        float* part = (float*)(wt + wt_elems);
        hipFuncSetAttribute((const void*)k_main8,
                            hipFuncAttributeMaxDynamicSharedMemorySize, 131072);
        int padq = (int)(((size_t)BATCH*HP*HP*64 + 255)/256);
        k_pad_convert<<<padq, 256, 0, stream>>>(in, in_p);
        k_wt_convert<<<9*CO, 256, 0, stream>>>(w_sh, wt);
        k_main8<<<512, 512, 131072, stream>>>(in_p, wt, b_sh, w_cls, w_dlt, part);
        k_finalize_ws<<<(NPIX + 255)/256, 256, 0, stream>>>(part, out, b_cls, b_dlt);
    } else {
        hipMemsetAsync(d_out, 0, (size_t)out_size * sizeof(float), stream);
        k_main_fb<<<2048, 256, 0, stream>>>(in, w_sh, b_sh, w_cls, w_dlt, out);
        k_finalize<<<(NPIX + 255)/256, 256, 0, stream>>>(out, b_cls, b_dlt);
    }
}